// Round 7
// baseline (358.901 us; speedup 1.0000x reference)
//
#include <hip/hip_runtime.h>
#include <stdint.h>

constexpr int NB = 32;    // batch
constexpr int NT = 2048;  // time
constexpr int NK = 1024;  // encoder hidden (K of GEMM)
constexpr int NH = 1024;  // attn hidden (N of GEMM)
constexpr int NQ = 1024;  // decoder hidden
constexpr int NTB = NT * NB;  // 65536 GEMM rows

typedef __attribute__((ext_vector_type(8))) short bf16x8;
typedef __attribute__((ext_vector_type(4))) float f32x4;

__device__ __forceinline__ short f2bf(float f) {
  union { float f; unsigned u; } c{f};
  unsigned r = (c.u + 0x7fffu + ((c.u >> 16) & 1u)) >> 16;
  return (short)r;
}

// tanh via hw exp: (e-1)/(e+1), e=exp(2x), clamped.  ~6 VALU ops.
__device__ __forceinline__ float fast_tanh(float x) {
  float e = __expf(fminf(fmaxf(x + x, -30.f), 30.f));
  return (e - 1.f) * __builtin_amdgcn_rcpf(e + 1.f);
}

__device__ __forceinline__ void gload16(const void* g, void* l) {
  __builtin_amdgcn_global_load_lds(
      (const __attribute__((address_space(1))) unsigned int*)g,
      (__attribute__((address_space(3))) unsigned int*)l, 16, 0, 0);
}

// ---------------------------------------------------------------------------
// Kernel 0: fp32 -> bf16 convert WITH baked LDS bank-swizzle.
// Within each 64-col K-slice (8 chunks of 8 elems), stored chunk c holds
// source chunk (c ^ (row&7)).  GEMM stages rows verbatim (linear gload_lds,
// LINEAR source) and un-swizzles on ds_read -> conflict-free (r4/r6: 0).
// ---------------------------------------------------------------------------
__global__ __launch_bounds__(256)
void convert_swz_kernel(const float* __restrict__ in, short* __restrict__ out,
                        long nchunks) {
  long stride = (long)gridDim.x * 256;
  for (long i = (long)blockIdx.x * 256 + threadIdx.x; i < nchunks; i += stride) {
    long r = i >> 7;            // 128 chunks per 1024-wide row
    int c = (int)(i & 127);
    int src = (c & ~7) | ((c & 7) ^ ((int)r & 7));
    const float* p = in + (r << 10) + (src << 3);
    float4 a = *(const float4*)p;
    float4 b = *(const float4*)(p + 4);
    bf16x8 o;
    o[0] = f2bf(a.x); o[1] = f2bf(a.y); o[2] = f2bf(a.z); o[3] = f2bf(a.w);
    o[4] = f2bf(b.x); o[5] = f2bf(b.y); o[6] = f2bf(b.z); o[7] = f2bf(b.w);
    *(bf16x8*)(out + (i << 3)) = o;
  }
}

// ---------------------------------------------------------------------------
// Kernel 1: query[b][h] = sum_q dec[b][q] * Wq[h][q]  (fp32, tiny)
// ---------------------------------------------------------------------------
__global__ __launch_bounds__(256)
void query_kernel(const float* __restrict__ dec, const float* __restrict__ Wq,
                  float* __restrict__ query) {
  int b = blockIdx.x;
  int h0 = blockIdx.y * 64;
  __shared__ float sdec[NQ];
  for (int i = threadIdx.x; i < NQ; i += 256) sdec[i] = dec[b * NQ + i];
  __syncthreads();
  int hl = threadIdx.x >> 2;
  int p  = threadIdx.x & 3;
  int h = h0 + hl;
  const float* wrow = Wq + (size_t)h * NQ;
  float s = 0.f;
  for (int k = p * 4; k < NQ; k += 16) {
    float4 w = *(const float4*)(wrow + k);
    float4 d = *(const float4*)(sdec + k);
    s += w.x * d.x + w.y * d.y + w.z * d.z + w.w * d.w;
  }
  s += __shfl_xor(s, 1);
  s += __shfl_xor(s, 2);
  if (p == 0) query[b * NH + h] = s;
}

// ---------------------------------------------------------------------------
// Kernel 2: ring-3 counted-vmcnt bf16-MFMA GEMM, 2-PHASE per K-iter,
// setprio-wrapped pure-MFMA clusters (T3-lite + T5), fused tanh/v epilogue.
// BM=256, BN=128, BK=64, 512 threads = 8 waves (4M x 2N), 64x64 out/wave.
// LDS ring of 3 slots: A 3x32KB + B 3x16KB = 144KB dynamic, 1 block/CU.
// Iter t: boundary {lgkmcnt(0) vmcnt(6); s_barrier} then 2 phases (ks=0,1):
//   phase: 8x ds_read_b128 -> 3x gload_lds (stage t+2, spread) -> s_barrier
//          -> lgkmcnt(0) -> setprio(1) -> 16 MFMA -> setprio(0) -> s_barrier
// vmcnt(6): stage(t+1)'s 6 loads stay in flight across the boundary.
// WAR on slot (t+2)%3=(t-1)%3: every phase's reads are consumed by its own
// MFMAs before its closing barrier, so iter t-1's reads are done before any
// wave's iter-t stage writes can land.
// ---------------------------------------------------------------------------
__global__ __launch_bounds__(512, 2)
void scores_mfma_kernel(const short* __restrict__ Ebf, const short* __restrict__ Wkbf,
                        const float* __restrict__ query, const float* __restrict__ v,
                        float* __restrict__ scores) {
  extern __shared__ short smem[];
  short* lA = smem;                    // 3 * 256*64 shorts
  short* lB = smem + 3 * 256 * 64;     // 3 * 128*64 shorts

  const int bid = blockIdx.x;
  const int x  = bid & 7;                  // XCD
  const int ht = (bid >> 3) & 7;           // NH/128 = 8, fast on XCD
  const int rt = ((bid >> 6) << 3) + x;    // 0..255
  const int rowBase = rt * 256;
  const int hBase   = ht * 128;

  const int tid  = threadIdx.x;
  const int lane = tid & 63;
  const int l15  = lane & 15;
  const int lhi  = lane >> 4;
  const int wid  = tid >> 6;      // 0..7
  const int wm   = wid >> 1;      // 0..3 : 64-row band
  const int wn   = wid & 1;       // 0..1 : 64-col band

  const int srow = tid >> 3;      // 0..63 staging row within round
  const int sc   = lane & 7;      // staging chunk

  f32x4 acc[4][4] = {};

  // stage halves: half 0 = A rounds 0,1 + B round 0; half 1 = A rounds 2,3 + B round 1
  auto STAGE_H0 = [&](int slot, int t) {
    const int k0 = t << 6;
    short* la = lA + slot * (256 * 64);
    short* lb = lB + slot * (128 * 64);
    const int src = k0 + (sc << 3);   // LINEAR: swizzle baked in Ebf/Wkbf
    gload16(Ebf + (size_t)(rowBase + srow) * NK + src,        la + srow * 64 + (sc << 3));
    gload16(Ebf + (size_t)(rowBase + 64 + srow) * NK + src,   la + (64 + srow) * 64 + (sc << 3));
    gload16(Wkbf + (size_t)(hBase + srow) * NK + src,         lb + srow * 64 + (sc << 3));
  };
  auto STAGE_H1 = [&](int slot, int t) {
    const int k0 = t << 6;
    short* la = lA + slot * (256 * 64);
    short* lb = lB + slot * (128 * 64);
    const int src = k0 + (sc << 3);
    gload16(Ebf + (size_t)(rowBase + 128 + srow) * NK + src,  la + (128 + srow) * 64 + (sc << 3));
    gload16(Ebf + (size_t)(rowBase + 192 + srow) * NK + src,  la + (192 + srow) * 64 + (sc << 3));
    gload16(Wkbf + (size_t)(hBase + 64 + srow) * NK + src,    lb + (64 + srow) * 64 + (sc << 3));
  };

  // prologue: 12 loads outstanding entering t=0
  STAGE_H0(0, 0); STAGE_H1(0, 0);
  STAGE_H0(1, 1); STAGE_H1(1, 1);

  for (int t = 0; t < 16; ++t) {
    const int slot = t % 3;
    if (t < 15) {
      asm volatile("s_waitcnt lgkmcnt(0) vmcnt(6)" ::: "memory");
    } else {
      asm volatile("s_waitcnt lgkmcnt(0) vmcnt(0)" ::: "memory");
    }
    __builtin_amdgcn_s_barrier();

    const short* la = lA + slot * (256 * 64);
    const short* lb = lB + slot * (128 * 64);

    // ---------------- phase 0: ks = 0 ----------------
    {
      bf16x8 af[4], bg[4];
#pragma unroll
      for (int m = 0; m < 4; ++m) {
        const int row = wm * 64 + m * 16 + l15;
        const int ch = (lhi ^ (row & 7)) << 3;           // ks=0
        af[m] = *(const bf16x8*)(la + row * 64 + ch);
      }
#pragma unroll
      for (int n = 0; n < 4; ++n) {
        const int row = wn * 64 + n * 16 + l15;
        const int ch = (lhi ^ (row & 7)) << 3;
        bg[n] = *(const bf16x8*)(lb + row * 64 + ch);
      }
      if (t < 14) STAGE_H0((t + 2) % 3, t + 2);
      __builtin_amdgcn_s_barrier();
      asm volatile("s_waitcnt lgkmcnt(0)" ::: "memory");
      __builtin_amdgcn_s_setprio(1);
#pragma unroll
      for (int m = 0; m < 4; ++m)
#pragma unroll
        for (int n = 0; n < 4; ++n)
          acc[m][n] = __builtin_amdgcn_mfma_f32_16x16x32_bf16(af[m], bg[n], acc[m][n], 0, 0, 0);
      __builtin_amdgcn_s_setprio(0);
      __builtin_amdgcn_s_barrier();
    }
    // ---------------- phase 1: ks = 1 ----------------
    {
      bf16x8 af[4], bg[4];
#pragma unroll
      for (int m = 0; m < 4; ++m) {
        const int row = wm * 64 + m * 16 + l15;
        const int ch = ((4 + lhi) ^ (row & 7)) << 3;     // ks=1
        af[m] = *(const bf16x8*)(la + row * 64 + ch);
      }
#pragma unroll
      for (int n = 0; n < 4; ++n) {
        const int row = wn * 64 + n * 16 + l15;
        const int ch = ((4 + lhi) ^ (row & 7)) << 3;
        bg[n] = *(const bf16x8*)(lb + row * 64 + ch);
      }
      if (t < 14) STAGE_H1((t + 2) % 3, t + 2);
      __builtin_amdgcn_s_barrier();
      asm volatile("s_waitcnt lgkmcnt(0)" ::: "memory");
      __builtin_amdgcn_s_setprio(1);
#pragma unroll
      for (int m = 0; m < 4; ++m)
#pragma unroll
        for (int n = 0; n < 4; ++n)
          acc[m][n] = __builtin_amdgcn_mfma_f32_16x16x32_bf16(af[m], bg[n], acc[m][n], 0, 0, 0);
      __builtin_amdgcn_s_setprio(0);
      __builtin_amdgcn_s_barrier();
    }
  }

  // epilogue: fast-tanh + v-dot, shfl-reduce over 16 col-lanes, atomic partial
  // C/D layout: col = lane&15, row = (lane>>4)*4 + reg  [m89-verified]
#pragma unroll
  for (int m = 0; m < 4; ++m) {
#pragma unroll
    for (int reg = 0; reg < 4; ++reg) {
      int row = rowBase + wm * 64 + m * 16 + lhi * 4 + reg;
      int b = row & (NB - 1);
      float s = 0.f;
#pragma unroll
      for (int n = 0; n < 4; ++n) {
        int col = hBase + wn * 64 + n * 16 + l15;
        float c = acc[m][n][reg];
        s += fast_tanh(c + query[b * NH + col]) * v[col];
      }
      s += __shfl_xor(s, 1);
      s += __shfl_xor(s, 2);
      s += __shfl_xor(s, 4);
      s += __shfl_xor(s, 8);
      if (l15 == 0) atomicAdd(&scores[row], s);
    }
  }
}

// ---------------------------------------------------------------------------
// Kernel 2 (fallback, small-ws): fp32 reg-staged version (round-2, correct).
// ---------------------------------------------------------------------------
__global__ __launch_bounds__(256)
void scores_kernel_f32(const float* __restrict__ E, const float* __restrict__ Wk,
                       const float* __restrict__ query, const float* __restrict__ v,
                       float* __restrict__ scores) {
  const int bid = blockIdx.x;
  const int x  = bid & 7;
  const int ht = (bid >> 3) & 7;
  const int rt = x + ((bid >> 6) << 3);
  const int rowBase = rt * 128;
  const int hBase   = ht * 128;

  __shared__ short lA[128][72];
  __shared__ short lB[128][72];

  const int tid = threadIdx.x;
  const int lane = tid & 63;
  const int l15 = lane & 15;
  const int lhi = lane >> 4;
  const int wid = tid >> 6;
  const int wm = wid >> 1;
  const int wn = wid & 1;

  const int rq = tid >> 3;
  const int kq = (tid & 7) << 3;

  f32x4 acc[4][4] = {};

  for (int k0 = 0; k0 < NK; k0 += 64) {
    __syncthreads();
#pragma unroll
    for (int q = 0; q < 4; ++q) {
      int r = rq + q * 32;
      const float* pe = E  + (size_t)(rowBase + r) * NK + k0 + kq;
      const float* pw = Wk + (size_t)(hBase  + r) * NK + k0 + kq;
      float4 e0 = *(const float4*)(pe);
      float4 e1 = *(const float4*)(pe + 4);
      float4 w0 = *(const float4*)(pw);
      float4 w1 = *(const float4*)(pw + 4);
      bf16x8 se, sw;
      se[0] = f2bf(e0.x); se[1] = f2bf(e0.y); se[2] = f2bf(e0.z); se[3] = f2bf(e0.w);
      se[4] = f2bf(e1.x); se[5] = f2bf(e1.y); se[6] = f2bf(e1.z); se[7] = f2bf(e1.w);
      sw[0] = f2bf(w0.x); sw[1] = f2bf(w0.y); sw[2] = f2bf(w0.z); sw[3] = f2bf(w0.w);
      sw[4] = f2bf(w1.x); sw[5] = f2bf(w1.y); sw[6] = f2bf(w1.z); sw[7] = f2bf(w1.w);
      *(bf16x8*)&lA[r][kq] = se;
      *(bf16x8*)&lB[r][kq] = sw;
    }
    __syncthreads();

#pragma unroll
    for (int ks = 0; ks < 2; ++ks) {
      const int kk = ks * 32 + lhi * 8;
      bf16x8 af[4], bfr[4];
#pragma unroll
      for (int m = 0; m < 4; ++m)
        af[m] = *(const bf16x8*)&lA[wm * 64 + m * 16 + l15][kk];
#pragma unroll
      for (int n = 0; n < 4; ++n)
        bfr[n] = *(const bf16x8*)&lB[wn * 64 + n * 16 + l15][kk];
#pragma unroll
      for (int m = 0; m < 4; ++m)
#pragma unroll
        for (int n = 0; n < 4; ++n)
          acc[m][n] = __builtin_amdgcn_mfma_f32_16x16x32_bf16(af[m], bfr[n], acc[m][n], 0, 0, 0);
    }
  }

#pragma unroll
  for (int m = 0; m < 4; ++m) {
#pragma unroll
    for (int reg = 0; reg < 4; ++reg) {
      int row = rowBase + wm * 64 + m * 16 + lhi * 4 + reg;
      int b = row & (NB - 1);
      float s = 0.f;
#pragma unroll
      for (int n = 0; n < 4; ++n) {
        int col = hBase + wn * 64 + n * 16 + l15;
        float c = acc[m][n][reg];
        s += fast_tanh(c + query[b * NH + col]) * v[col];
      }
      s += __shfl_xor(s, 1);
      s += __shfl_xor(s, 2);
      s += __shfl_xor(s, 4);
      s += __shfl_xor(s, 8);
      if (l15 == 0) atomicAdd(&scores[row], s);
    }
  }
}

// ---------------------------------------------------------------------------
// Kernel 3: masked softmax over t, per b.  In-place scores -> alphas.
// ---------------------------------------------------------------------------
__global__ __launch_bounds__(256)
void softmax_kernel(const int* __restrict__ mask, float* __restrict__ alphas) {
  int b = blockIdx.x;
  int tid = threadIdx.x;
  float sv[8];
  int mv[8];
  float mx = -INFINITY;
#pragma unroll
  for (int i = 0; i < 8; ++i) {
    int t = tid + i * 256;
    sv[i] = alphas[t * NB + b];
    mv[i] = mask[t * NB + b];
    if (mv[i] != 0) mx = fmaxf(mx, sv[i]);
  }
  __shared__ float red[256];
  red[tid] = mx;
  __syncthreads();
  for (int o = 128; o > 0; o >>= 1) {
    if (tid < o) red[tid] = fmaxf(red[tid], red[tid + o]);
    __syncthreads();
  }
  mx = red[0];
  __syncthreads();
  float sum = 0.f;
#pragma unroll
  for (int i = 0; i < 8; ++i) {
    if (mv[i] != 0) { sv[i] = expf(sv[i] - mx); sum += sv[i]; }
    else sv[i] = 0.f;
  }
  red[tid] = sum;
  __syncthreads();
  for (int o = 128; o > 0; o >>= 1) {
    if (tid < o) red[tid] += red[tid + o];
    __syncthreads();
  }
  float inv = 1.f / red[0];
#pragma unroll
  for (int i = 0; i < 8; ++i) {
    int t = tid + i * 256;
    alphas[t * NB + b] = sv[i] * inv;
  }
}

// ---------------------------------------------------------------------------
// Kernel 4: context[b][k] = sum_t alphas[t][b] * E[t][b][k]  (fp32 E)
// ---------------------------------------------------------------------------
__global__ __launch_bounds__(256)
void context_kernel(const float* __restrict__ E, const float* __restrict__ alphas,
                    float* __restrict__ ctx) {
  int k = blockIdx.x * 256 + threadIdx.x;
  int b = blockIdx.y;
  int t0 = blockIdx.z * 128;
  float acc = 0.f;
  for (int t = t0; t < t0 + 128; ++t) {
    float a = alphas[t * NB + b];
    acc = fmaf(a, E[((size_t)t * NB + b) * NK + k], acc);
  }
  atomicAdd(&ctx[b * NK + k], acc);
}

// ---------------------------------------------------------------------------
extern "C" void kernel_launch(void* const* d_in, const int* in_sizes, int n_in,
                              void* d_out, int out_size, void* d_ws, size_t ws_size,
                              hipStream_t stream) {
  const float* dec  = (const float*)d_in[0];
  const float* enc  = (const float*)d_in[1];
  const int*   mask = (const int*)d_in[2];
  const float* Wk   = (const float*)d_in[3];
  const float* Wq   = (const float*)d_in[4];
  const float* v    = (const float*)d_in[5];

  float* ctx    = (float*)d_out;
  float* alphas = (float*)d_out + NB * NK;

  const size_t QUERY_B = (size_t)NB * NH * sizeof(float);            // 128 KB
  const size_t WKBF_B  = (size_t)NH * NK * sizeof(short);            // 2 MB
  const size_t EBF_B   = (size_t)NTB * NK * sizeof(short);           // 128 MB
  float* query = (float*)d_ws;
  short* Wkbf  = (short*)((char*)d_ws + QUERY_B);
  short* Ebf   = (short*)((char*)d_ws + QUERY_B + WKBF_B);
  const bool fast = ws_size >= QUERY_B + WKBF_B + EBF_B;

  hipMemsetAsync(d_out, 0, (size_t)out_size * sizeof(float), stream);

  query_kernel<<<dim3(NB, NH / 64), 256, 0, stream>>>(dec, Wq, query);
  if (fast) {
    convert_swz_kernel<<<dim3(2048), 256, 0, stream>>>(enc, Ebf, (long)NTB * NK / 8);
    convert_swz_kernel<<<dim3(512), 256, 0, stream>>>(Wk, Wkbf, (long)NH * NK / 8);
    const int SMEM = (3 * 256 * 64 + 3 * 128 * 64) * (int)sizeof(short);  // 144 KB
    hipFuncSetAttribute((const void*)scores_mfma_kernel,
                        hipFuncAttributeMaxDynamicSharedMemorySize, SMEM);
    scores_mfma_kernel<<<dim3((NTB / 256) * (NH / 128)), dim3(512), SMEM, stream>>>(
        Ebf, Wkbf, query, v, alphas);
  } else {
    scores_kernel_f32<<<dim3((NTB / 128) * (NH / 128)), 256, 0, stream>>>(
        enc, Wk, query, v, alphas);
  }
  softmax_kernel<<<dim3(NB), 256, 0, stream>>>(mask, alphas);
  context_kernel<<<dim3(NK / 256, NB, NT / 128), 256, 0, stream>>>(enc, alphas, ctx);
}

// Round 8
// 319.335 us; speedup vs baseline: 1.1239x; 1.1239x over previous
//
#include <hip/hip_runtime.h>
#include <stdint.h>

constexpr int NB = 32;    // batch
constexpr int NT = 2048;  // time
constexpr int NK = 1024;  // encoder hidden (K of GEMM)
constexpr int NH = 1024;  // attn hidden (N of GEMM)
constexpr int NQ = 1024;  // decoder hidden
constexpr int NTB = NT * NB;  // 65536 GEMM rows

typedef __attribute__((ext_vector_type(8))) short bf16x8;
typedef __attribute__((ext_vector_type(4))) float f32x4;

__device__ __forceinline__ short f2bf(float f) {
  union { float f; unsigned u; } c{f};
  unsigned r = (c.u + 0x7fffu + ((c.u >> 16) & 1u)) >> 16;
  return (short)r;
}

// tanh via hw exp: (e-1)/(e+1), e=exp(2x), clamped.  ~6 VALU ops.
__device__ __forceinline__ float fast_tanh(float x) {
  float e = __expf(fminf(fmaxf(x + x, -30.f), 30.f));
  return (e - 1.f) * __builtin_amdgcn_rcpf(e + 1.f);
}

__device__ __forceinline__ void gload16(const void* g, void* l) {
  __builtin_amdgcn_global_load_lds(
      (const __attribute__((address_space(1))) unsigned int*)g,
      (__attribute__((address_space(3))) unsigned int*)l, 16, 0, 0);
}

// ---------------------------------------------------------------------------
// Kernel 0: fp32 -> bf16 convert WITH baked LDS bank-swizzle.
// Within each 64-col K-slice (8 chunks of 8 elems), stored chunk c holds
// source chunk (c ^ (row&7)).  GEMM stages rows verbatim (linear gload_lds,
// LINEAR source) and un-swizzles on ds_read -> conflict-free (r4/r6: 0).
// ---------------------------------------------------------------------------
__global__ __launch_bounds__(256)
void convert_swz_kernel(const float* __restrict__ in, short* __restrict__ out,
                        long nchunks) {
  long stride = (long)gridDim.x * 256;
  for (long i = (long)blockIdx.x * 256 + threadIdx.x; i < nchunks; i += stride) {
    long r = i >> 7;            // 128 chunks per 1024-wide row
    int c = (int)(i & 127);
    int src = (c & ~7) | ((c & 7) ^ ((int)r & 7));
    const float* p = in + (r << 10) + (src << 3);
    float4 a = *(const float4*)p;
    float4 b = *(const float4*)(p + 4);
    bf16x8 o;
    o[0] = f2bf(a.x); o[1] = f2bf(a.y); o[2] = f2bf(a.z); o[3] = f2bf(a.w);
    o[4] = f2bf(b.x); o[5] = f2bf(b.y); o[6] = f2bf(b.z); o[7] = f2bf(b.w);
    *(bf16x8*)(out + (i << 3)) = o;
  }
}

// ---------------------------------------------------------------------------
// Kernel 1: query[b][h] = sum_q dec[b][q] * Wq[h][q]  (fp32, tiny)
// ---------------------------------------------------------------------------
__global__ __launch_bounds__(256)
void query_kernel(const float* __restrict__ dec, const float* __restrict__ Wq,
                  float* __restrict__ query) {
  int b = blockIdx.x;
  int h0 = blockIdx.y * 64;
  __shared__ float sdec[NQ];
  for (int i = threadIdx.x; i < NQ; i += 256) sdec[i] = dec[b * NQ + i];
  __syncthreads();
  int hl = threadIdx.x >> 2;
  int p  = threadIdx.x & 3;
  int h = h0 + hl;
  const float* wrow = Wq + (size_t)h * NQ;
  float s = 0.f;
  for (int k = p * 4; k < NQ; k += 16) {
    float4 w = *(const float4*)(wrow + k);
    float4 d = *(const float4*)(sdec + k);
    s += w.x * d.x + w.y * d.y + w.z * d.z + w.w * d.w;
  }
  s += __shfl_xor(s, 1);
  s += __shfl_xor(s, 2);
  if (p == 0) query[b * NH + h] = s;
}

// ---------------------------------------------------------------------------
// Kernel 2: m97-geometry bf16-MFMA GEMM + fused fast-tanh/v-dot scores.
// 128x128 tile, BK=64, 4 waves (2x2), 64x64 out/wave, single 32 KB LDS buf,
// 2 __syncthreads per K-iter (m97-measured 874-912 TF at this shape).
// 32 KB LDS + VGPR<=128 (launch_bounds 256,4) -> ~4 blocks/CU co-resident:
// cross-block wave overlap hides the barrier/vmcnt drain (m114 mechanism).
// Staging: 8x gload16/thread (4 A + 4 B), LINEAR source (swizzle pre-baked);
// ds_read un-swizzles chunk^(row&7): conflict-free (r4/r6 verified, 0).
// ---------------------------------------------------------------------------
__global__ __launch_bounds__(256, 4)
void scores_mfma_kernel(const short* __restrict__ Ebf, const short* __restrict__ Wkbf,
                        const float* __restrict__ query, const float* __restrict__ v,
                        float* __restrict__ scores) {
  __shared__ short lA[128 * 64];  // 16 KB
  __shared__ short lB[128 * 64];  // 16 KB

  const int bid = blockIdx.x;
  const int x  = bid & 7;                  // XCD
  const int ht = (bid >> 3) & 7;           // NH/128 = 8, fast on XCD
  const int rt = ((bid >> 6) << 3) + x;    // 0..511
  const int rowBase = rt * 128;
  const int hBase   = ht * 128;

  const int tid  = threadIdx.x;
  const int lane = tid & 63;
  const int l15  = lane & 15;
  const int lhi  = lane >> 4;
  const int wid  = tid >> 6;      // 0..3
  const int wm   = wid >> 1;      // 0..1
  const int wn   = wid & 1;       // 0..1

  const int srow = tid >> 3;      // 0..31 staging row within round
  const int sc   = tid & 7;       // staging chunk
  // LDS dest per round q: q*4096 + tid*16 bytes (wave-uniform base + lane*16) ✓
  const int ldsOffS = tid << 3;   // shorts

  f32x4 acc[4][4] = {};

  for (int t = 0; t < 16; ++t) {
    const int k0 = t << 6;
    const int src = k0 + (sc << 3);   // LINEAR: swizzle baked in Ebf/Wkbf
    __syncthreads();                  // prev iter's reads done before overwrite
#pragma unroll
    for (int q = 0; q < 4; ++q) {
      const int row = q * 32 + srow;
      gload16(Ebf  + (size_t)(rowBase + row) * NK + src, &lA[(q << 11) + ldsOffS]);
      gload16(Wkbf + (size_t)(hBase  + row) * NK + src, &lB[(q << 11) + ldsOffS]);
    }
    __syncthreads();                  // drains vmcnt -> tile visible

#pragma unroll
    for (int ks = 0; ks < 2; ++ks) {
      bf16x8 af[4], bg[4];
#pragma unroll
      for (int m = 0; m < 4; ++m) {
        const int row = wm * 64 + m * 16 + l15;
        const int ch = ((ks * 4 + lhi) ^ (row & 7)) << 3;
        af[m] = *(const bf16x8*)&lA[row * 64 + ch];
      }
#pragma unroll
      for (int n = 0; n < 4; ++n) {
        const int row = wn * 64 + n * 16 + l15;
        const int ch = ((ks * 4 + lhi) ^ (row & 7)) << 3;
        bg[n] = *(const bf16x8*)&lB[row * 64 + ch];
      }
#pragma unroll
      for (int m = 0; m < 4; ++m)
#pragma unroll
        for (int n = 0; n < 4; ++n)
          acc[m][n] = __builtin_amdgcn_mfma_f32_16x16x32_bf16(af[m], bg[n], acc[m][n], 0, 0, 0);
    }
  }

  // epilogue: fast-tanh + v-dot, shfl-reduce over 16 col-lanes, atomic partial
  // C/D layout: col = lane&15, row = (lane>>4)*4 + reg  [m89-verified]
#pragma unroll
  for (int m = 0; m < 4; ++m) {
#pragma unroll
    for (int reg = 0; reg < 4; ++reg) {
      int row = rowBase + wm * 64 + m * 16 + lhi * 4 + reg;
      int b = row & (NB - 1);
      float s = 0.f;
#pragma unroll
      for (int n = 0; n < 4; ++n) {
        int col = hBase + wn * 64 + n * 16 + l15;
        float c = acc[m][n][reg];
        s += fast_tanh(c + query[b * NH + col]) * v[col];
      }
      s += __shfl_xor(s, 1);
      s += __shfl_xor(s, 2);
      s += __shfl_xor(s, 4);
      s += __shfl_xor(s, 8);
      if (l15 == 0) atomicAdd(&scores[row], s);
    }
  }
}

// ---------------------------------------------------------------------------
// Kernel 2 (fallback, small-ws): fp32 reg-staged version (round-2, correct).
// ---------------------------------------------------------------------------
__global__ __launch_bounds__(256)
void scores_kernel_f32(const float* __restrict__ E, const float* __restrict__ Wk,
                       const float* __restrict__ query, const float* __restrict__ v,
                       float* __restrict__ scores) {
  const int bid = blockIdx.x;
  const int x  = bid & 7;
  const int ht = (bid >> 3) & 7;
  const int rt = x + ((bid >> 6) << 3);
  const int rowBase = rt * 128;
  const int hBase   = ht * 128;

  __shared__ short lA[128][72];
  __shared__ short lB[128][72];

  const int tid = threadIdx.x;
  const int lane = tid & 63;
  const int l15 = lane & 15;
  const int lhi = lane >> 4;
  const int wid = tid >> 6;
  const int wm = wid >> 1;
  const int wn = wid & 1;

  const int rq = tid >> 3;
  const int kq = (tid & 7) << 3;

  f32x4 acc[4][4] = {};

  for (int k0 = 0; k0 < NK; k0 += 64) {
    __syncthreads();
#pragma unroll
    for (int q = 0; q < 4; ++q) {
      int r = rq + q * 32;
      const float* pe = E  + (size_t)(rowBase + r) * NK + k0 + kq;
      const float* pw = Wk + (size_t)(hBase  + r) * NK + k0 + kq;
      float4 e0 = *(const float4*)(pe);
      float4 e1 = *(const float4*)(pe + 4);
      float4 w0 = *(const float4*)(pw);
      float4 w1 = *(const float4*)(pw + 4);
      bf16x8 se, sw;
      se[0] = f2bf(e0.x); se[1] = f2bf(e0.y); se[2] = f2bf(e0.z); se[3] = f2bf(e0.w);
      se[4] = f2bf(e1.x); se[5] = f2bf(e1.y); se[6] = f2bf(e1.z); se[7] = f2bf(e1.w);
      sw[0] = f2bf(w0.x); sw[1] = f2bf(w0.y); sw[2] = f2bf(w0.z); sw[3] = f2bf(w0.w);
      sw[4] = f2bf(w1.x); sw[5] = f2bf(w1.y); sw[6] = f2bf(w1.z); sw[7] = f2bf(w1.w);
      *(bf16x8*)&lA[r][kq] = se;
      *(bf16x8*)&lB[r][kq] = sw;
    }
    __syncthreads();

#pragma unroll
    for (int ks = 0; ks < 2; ++ks) {
      const int kk = ks * 32 + lhi * 8;
      bf16x8 af[4], bfr[4];
#pragma unroll
      for (int m = 0; m < 4; ++m)
        af[m] = *(const bf16x8*)&lA[wm * 64 + m * 16 + l15][kk];
#pragma unroll
      for (int n = 0; n < 4; ++n)
        bfr[n] = *(const bf16x8*)&lB[wn * 64 + n * 16 + l15][kk];
#pragma unroll
      for (int m = 0; m < 4; ++m)
#pragma unroll
        for (int n = 0; n < 4; ++n)
          acc[m][n] = __builtin_amdgcn_mfma_f32_16x16x32_bf16(af[m], bfr[n], acc[m][n], 0, 0, 0);
    }
  }

#pragma unroll
  for (int m = 0; m < 4; ++m) {
#pragma unroll
    for (int reg = 0; reg < 4; ++reg) {
      int row = rowBase + wm * 64 + m * 16 + lhi * 4 + reg;
      int b = row & (NB - 1);
      float s = 0.f;
#pragma unroll
      for (int n = 0; n < 4; ++n) {
        int col = hBase + wn * 64 + n * 16 + l15;
        float c = acc[m][n][reg];
        s += fast_tanh(c + query[b * NH + col]) * v[col];
      }
      s += __shfl_xor(s, 1);
      s += __shfl_xor(s, 2);
      s += __shfl_xor(s, 4);
      s += __shfl_xor(s, 8);
      if (l15 == 0) atomicAdd(&scores[row], s);
    }
  }
}

// ---------------------------------------------------------------------------
// Kernel 3: masked softmax over t, per b.  In-place scores -> alphas.
// ---------------------------------------------------------------------------
__global__ __launch_bounds__(256)
void softmax_kernel(const int* __restrict__ mask, float* __restrict__ alphas) {
  int b = blockIdx.x;
  int tid = threadIdx.x;
  float sv[8];
  int mv[8];
  float mx = -INFINITY;
#pragma unroll
  for (int i = 0; i < 8; ++i) {
    int t = tid + i * 256;
    sv[i] = alphas[t * NB + b];
    mv[i] = mask[t * NB + b];
    if (mv[i] != 0) mx = fmaxf(mx, sv[i]);
  }
  __shared__ float red[256];
  red[tid] = mx;
  __syncthreads();
  for (int o = 128; o > 0; o >>= 1) {
    if (tid < o) red[tid] = fmaxf(red[tid], red[tid + o]);
    __syncthreads();
  }
  mx = red[0];
  __syncthreads();
  float sum = 0.f;
#pragma unroll
  for (int i = 0; i < 8; ++i) {
    if (mv[i] != 0) { sv[i] = expf(sv[i] - mx); sum += sv[i]; }
    else sv[i] = 0.f;
  }
  red[tid] = sum;
  __syncthreads();
  for (int o = 128; o > 0; o >>= 1) {
    if (tid < o) red[tid] += red[tid + o];
    __syncthreads();
  }
  float inv = 1.f / red[0];
#pragma unroll
  for (int i = 0; i < 8; ++i) {
    int t = tid + i * 256;
    alphas[t * NB + b] = sv[i] * inv;
  }
}

// ---------------------------------------------------------------------------
// Kernel 4: context[b][k] = sum_t alphas[t][b] * E[t][b][k]  (fp32 E)
// ---------------------------------------------------------------------------
__global__ __launch_bounds__(256)
void context_kernel(const float* __restrict__ E, const float* __restrict__ alphas,
                    float* __restrict__ ctx) {
  int k = blockIdx.x * 256 + threadIdx.x;
  int b = blockIdx.y;
  int t0 = blockIdx.z * 128;
  float acc = 0.f;
  for (int t = t0; t < t0 + 128; ++t) {
    float a = alphas[t * NB + b];
    acc = fmaf(a, E[((size_t)t * NB + b) * NK + k], acc);
  }
  atomicAdd(&ctx[b * NK + k], acc);
}

// ---------------------------------------------------------------------------
extern "C" void kernel_launch(void* const* d_in, const int* in_sizes, int n_in,
                              void* d_out, int out_size, void* d_ws, size_t ws_size,
                              hipStream_t stream) {
  const float* dec  = (const float*)d_in[0];
  const float* enc  = (const float*)d_in[1];
  const int*   mask = (const int*)d_in[2];
  const float* Wk   = (const float*)d_in[3];
  const float* Wq   = (const float*)d_in[4];
  const float* v    = (const float*)d_in[5];

  float* ctx    = (float*)d_out;
  float* alphas = (float*)d_out + NB * NK;

  const size_t QUERY_B = (size_t)NB * NH * sizeof(float);            // 128 KB
  const size_t WKBF_B  = (size_t)NH * NK * sizeof(short);            // 2 MB
  const size_t EBF_B   = (size_t)NTB * NK * sizeof(short);           // 128 MB
  float* query = (float*)d_ws;
  short* Wkbf  = (short*)((char*)d_ws + QUERY_B);
  short* Ebf   = (short*)((char*)d_ws + QUERY_B + WKBF_B);
  const bool fast = ws_size >= QUERY_B + WKBF_B + EBF_B;

  hipMemsetAsync(d_out, 0, (size_t)out_size * sizeof(float), stream);

  query_kernel<<<dim3(NB, NH / 64), 256, 0, stream>>>(dec, Wq, query);
  if (fast) {
    convert_swz_kernel<<<dim3(2048), 256, 0, stream>>>(enc, Ebf, (long)NTB * NK / 8);
    convert_swz_kernel<<<dim3(512), 256, 0, stream>>>(Wk, Wkbf, (long)NH * NK / 8);
    scores_mfma_kernel<<<dim3((NTB / 128) * (NH / 128)), 256, 0, stream>>>(
        Ebf, Wkbf, query, v, alphas);
  } else {
    scores_kernel_f32<<<dim3((NTB / 128) * (NH / 128)), 256, 0, stream>>>(
        enc, Wk, query, v, alphas);
  }
  softmax_kernel<<<dim3(NB), 256, 0, stream>>>(mask, alphas);
  context_kernel<<<dim3(NK / 256, NB, NT / 128), 256, 0, stream>>>(enc, alphas, ctx);
}

// Round 9
// 307.258 us; speedup vs baseline: 1.1681x; 1.0393x over previous
//
#include <hip/hip_runtime.h>
#include <stdint.h>

constexpr int NB = 32;    // batch
constexpr int NT = 2048;  // time
constexpr int NK = 1024;  // encoder hidden (K of GEMM)
constexpr int NH = 1024;  // attn hidden (N of GEMM)
constexpr int NQ = 1024;  // decoder hidden
constexpr int NTB = NT * NB;  // 65536 GEMM rows

typedef __attribute__((ext_vector_type(8))) short bf16x8;
typedef __attribute__((ext_vector_type(4))) float f32x4;

__device__ __forceinline__ short f2bf(float f) {
  union { float f; unsigned u; } c{f};
  unsigned r = (c.u + 0x7fffu + ((c.u >> 16) & 1u)) >> 16;
  return (short)r;
}
__device__ __forceinline__ float bf2f(unsigned short u) {
  union { unsigned u; float f; } c{(unsigned)u << 16};
  return c.f;
}

// tanh via hw exp: (e-1)/(e+1), e=exp(2x), clamped.  ~6 VALU ops.
__device__ __forceinline__ float fast_tanh(float x) {
  float e = __expf(fminf(fmaxf(x + x, -30.f), 30.f));
  return (e - 1.f) * __builtin_amdgcn_rcpf(e + 1.f);
}

__device__ __forceinline__ void gload16(const void* g, void* l) {
  __builtin_amdgcn_global_load_lds(
      (const __attribute__((address_space(1))) unsigned int*)g,
      (__attribute__((address_space(3))) unsigned int*)l, 16, 0, 0);
}

// ---------------------------------------------------------------------------
// Kernel 0: fp32 -> bf16 convert WITH baked LDS bank-swizzle.
// Within each 64-col K-slice (8 chunks of 8 elems), stored chunk c holds
// source chunk (c ^ (row&7)).  GEMM stages rows verbatim (linear gload_lds,
// LINEAR source) and un-swizzles on ds_read -> conflict-free (r4/r6/r8: 0).
// ---------------------------------------------------------------------------
__global__ __launch_bounds__(256)
void convert_swz_kernel(const float* __restrict__ in, short* __restrict__ out,
                        long nchunks) {
  long stride = (long)gridDim.x * 256;
  for (long i = (long)blockIdx.x * 256 + threadIdx.x; i < nchunks; i += stride) {
    long r = i >> 7;            // 128 chunks per 1024-wide row
    int c = (int)(i & 127);
    int src = (c & ~7) | ((c & 7) ^ ((int)r & 7));
    const float* p = in + (r << 10) + (src << 3);
    float4 a = *(const float4*)p;
    float4 b = *(const float4*)(p + 4);
    bf16x8 o;
    o[0] = f2bf(a.x); o[1] = f2bf(a.y); o[2] = f2bf(a.z); o[3] = f2bf(a.w);
    o[4] = f2bf(b.x); o[5] = f2bf(b.y); o[6] = f2bf(b.z); o[7] = f2bf(b.w);
    *(bf16x8*)(out + (i << 3)) = o;
  }
}

// ---------------------------------------------------------------------------
// Kernel 1: query[b][h] = sum_q dec[b][q] * Wq[h][q]  (fp32, tiny)
// ---------------------------------------------------------------------------
__global__ __launch_bounds__(256)
void query_kernel(const float* __restrict__ dec, const float* __restrict__ Wq,
                  float* __restrict__ query) {
  int b = blockIdx.x;
  int h0 = blockIdx.y * 64;
  __shared__ float sdec[NQ];
  for (int i = threadIdx.x; i < NQ; i += 256) sdec[i] = dec[b * NQ + i];
  __syncthreads();
  int hl = threadIdx.x >> 2;
  int p  = threadIdx.x & 3;
  int h = h0 + hl;
  const float* wrow = Wq + (size_t)h * NQ;
  float s = 0.f;
  for (int k = p * 4; k < NQ; k += 16) {
    float4 w = *(const float4*)(wrow + k);
    float4 d = *(const float4*)(sdec + k);
    s += w.x * d.x + w.y * d.y + w.z * d.z + w.w * d.w;
  }
  s += __shfl_xor(s, 1);
  s += __shfl_xor(s, 2);
  if (p == 0) query[b * NH + h] = s;
}

// ---------------------------------------------------------------------------
// Kernel 2: 256x256-tile 8-phase dbuf bf16-MFMA GEMM (T3+T4+T5) + fused
// fast-tanh/v-dot scores epilogue.
// BM=BN=256, BK=64, 512 thr = 8 waves (wm=wid>>2 in {0,1}, wn=wid&3).
// INTERLEAVED M-mapping: phase h uses A rows [h*128,h*128+128) only
// (wave wm's frags for phase h = rows h*128 + wm*64 + m*16), so each
// A-half's last read is >=1 full phase before its re-stage.
// LDS: buf0 = even K-tile {A 256x64, B 256x64}, buf1 = odd; 128 KB total.
// Per 2-K-tile iter: 8 phases, each {ds_read (8 or 4 b128); stage 1
// half-tile (2 gload16); [counted vmcnt]; s_barrier; setprio1; 16 MFMA;
// setprio0; s_barrier}.  Stage rotation and waits (leads 4-6 phases):
//   p0: B1(t1)      p1: A1(t1)  + vmcnt(8)
//   p2: A0(t0+2)    p3: B0(t0+2)+ vmcnt(6)   [u==7: vmcnt(2)]
//   p4: B1(t0+2)    p5: A1(t0+2)+ vmcnt(8)   [u==7: vmcnt(0)]
//   p6: A0(t1+2)    p7: B0(t1+2)+ vmcnt(6)   [u==7: none]
// RAW/WAR audited per phase incl. prologue (A0,B0,B1,A1 of t0; A0,B0 of t1;
// vmcnt(6)+barrier) and final-iter drain.  Never vmcnt(0) mid-loop.
// ds_read un-swizzles chunk^(row&7): conflict-free (r4/r6/r8 verified).
// ---------------------------------------------------------------------------
__global__ __launch_bounds__(512, 2)
void scores_mfma_kernel(const short* __restrict__ Ebf, const short* __restrict__ Wkbf,
                        const float* __restrict__ query, const float* __restrict__ v,
                        float* __restrict__ scores) {
  extern __shared__ short smem[];   // 2 * 32768 shorts = 128 KB

  const int bid  = blockIdx.x;          // 0..1023
  const int x    = bid & 7;             // XCD
  const int rest = bid >> 3;            // 0..127
  const int ht   = rest & 3;            // 4 h-tiles, fast on XCD
  const int rt   = ((rest >> 2) << 3) | x;   // 0..255
  const int rowBase = rt * 256;
  const int hBase   = ht * 256;

  const int tid  = threadIdx.x;
  const int lane = tid & 63;
  const int l15  = lane & 15;
  const int lhi  = lane >> 4;
  const int wid  = tid >> 6;      // 0..7
  const int wm   = wid >> 2;      // 0..1
  const int wn   = wid & 3;       // 0..3

  const short* la0 = smem;               // buf0 A (256x64)
  const short* lb0 = smem + 16384;       // buf0 B
  const short* la1 = smem + 32768;       // buf1 A
  const short* lb1 = smem + 49152;       // buf1 B

  bf16x8 af[4], bg0[4], bg1[4];
  f32x4 acc[2][4][4] = {};   // [h][m][n]

#define DS_A(LA, H, KS) do { _Pragma("unroll") \
  for (int m_ = 0; m_ < 4; ++m_) { \
    const int row_ = (H)*128 + wm*64 + m_*16 + l15; \
    af[m_] = *(const bf16x8*)((LA) + row_*64 + ((((KS)*4 + lhi) ^ (row_ & 7)) << 3)); } } while(0)

#define DS_B(LB, KS, BG) do { _Pragma("unroll") \
  for (int n_ = 0; n_ < 4; ++n_) { \
    const int row_ = wn*64 + n_*16 + l15; \
    (BG)[n_] = *(const bf16x8*)((LB) + row_*64 + ((((KS)*4 + lhi) ^ (row_ & 7)) << 3)); } } while(0)

#define MF(H, BG) do { __builtin_amdgcn_s_setprio(1); _Pragma("unroll") \
  for (int m_ = 0; m_ < 4; ++m_) { _Pragma("unroll") \
    for (int n_ = 0; n_ < 4; ++n_) \
      acc[H][m_][n_] = __builtin_amdgcn_mfma_f32_16x16x32_bf16(af[m_], (BG)[n_], acc[H][m_][n_], 0, 0, 0); } \
  __builtin_amdgcn_s_setprio(0); } while(0)

#define BAR __builtin_amdgcn_s_barrier()

  // stage half-tile (128 rows, 2 gload16/thread); LDS dest = base + tid*16B (linear)
#define ST_A(BUF, H, TILE) do { \
  short* dst_ = smem + (BUF)*32768 + (((H)*128 + (tid >> 3)) * 64) + ((tid & 7) << 3); \
  const short* g_ = Ebf + (size_t)(rowBase + (H)*128 + (tid >> 3)) * NK + ((TILE) << 6) + ((tid & 7) << 3); \
  gload16(g_, dst_); gload16(g_ + (size_t)64 * NK, dst_ + 4096); } while(0)

#define ST_B(BUF, H, TILE) do { \
  short* dst_ = smem + (BUF)*32768 + 16384 + (((H)*128 + (tid >> 3)) * 64) + ((tid & 7) << 3); \
  const short* g_ = Wkbf + (size_t)(hBase + (H)*128 + (tid >> 3)) * NK + ((TILE) << 6) + ((tid & 7) << 3); \
  gload16(g_, dst_); gload16(g_ + (size_t)64 * NK, dst_ + 4096); } while(0)

  // prologue: A0(0),B0(0),B1(0),A1(0),A0(1),B0(1) -- 12 loads, allow last 3 halves in flight
  ST_A(0, 0, 0); ST_B(0, 0, 0); ST_B(0, 1, 0); ST_A(0, 1, 0);
  ST_A(1, 0, 1); ST_B(1, 0, 1);
  asm volatile("s_waitcnt vmcnt(6)" ::: "memory");
  BAR;

  for (int u = 0; u < 8; ++u) {
    const int t1 = 2 * u + 1;
    const bool stg = (u < 7);
    // ---- tile t0 = 2u (buf0) ----
    // p0: (h0,ks0)
    DS_B(lb0, 0, bg0); DS_A(la0, 0, 0);
    ST_B(1, 1, t1);
    BAR; MF(0, bg0); BAR;
    // p1: (h0,ks1)
    DS_B(lb0, 1, bg1); DS_A(la0, 0, 1);
    ST_A(1, 1, t1);
    asm volatile("s_waitcnt vmcnt(8)" ::: "memory");
    BAR; MF(0, bg1); BAR;
    // p2: (h1,ks0)
    DS_A(la0, 1, 0);
    if (stg) ST_A(0, 0, t1 + 1);
    BAR; MF(1, bg0); BAR;
    // p3: (h1,ks1)
    DS_A(la0, 1, 1);
    if (stg) { ST_B(0, 0, t1 + 1); asm volatile("s_waitcnt vmcnt(6)" ::: "memory"); }
    else     { asm volatile("s_waitcnt vmcnt(2)" ::: "memory"); }
    BAR; MF(1, bg1); BAR;
    // ---- tile t1 = 2u+1 (buf1) ----
    // p4: (h0,ks0)
    DS_B(lb1, 0, bg0); DS_A(la1, 0, 0);
    if (stg) ST_B(0, 1, t1 + 1);
    BAR; MF(0, bg0); BAR;
    // p5: (h0,ks1)
    DS_B(lb1, 1, bg1); DS_A(la1, 0, 1);
    if (stg) { ST_A(0, 1, t1 + 1); asm volatile("s_waitcnt vmcnt(8)" ::: "memory"); }
    else     { asm volatile("s_waitcnt vmcnt(0)" ::: "memory"); }
    BAR; MF(0, bg1); BAR;
    // p6: (h1,ks0)
    DS_A(la1, 1, 0);
    if (stg) ST_A(1, 0, t1 + 2);
    BAR; MF(1, bg0); BAR;
    // p7: (h1,ks1)
    DS_A(la1, 1, 1);
    if (stg) { ST_B(1, 0, t1 + 2); asm volatile("s_waitcnt vmcnt(6)" ::: "memory"); }
    BAR; MF(1, bg1); BAR;
  }

  // epilogue: fast-tanh + v-dot, shfl-reduce over 16 col-lanes, atomic partial
  // C/D layout: col = lane&15, row = (lane>>4)*4 + reg  [m89-verified]
#pragma unroll
  for (int h = 0; h < 2; ++h) {
#pragma unroll
    for (int m = 0; m < 4; ++m) {
#pragma unroll
      for (int reg = 0; reg < 4; ++reg) {
        int row = rowBase + h * 128 + wm * 64 + m * 16 + lhi * 4 + reg;
        int b = row & (NB - 1);
        float s = 0.f;
#pragma unroll
        for (int n = 0; n < 4; ++n) {
          int col = hBase + wn * 64 + n * 16 + l15;
          float c = acc[h][m][n][reg];
          s += fast_tanh(c + query[b * NH + col]) * v[col];
        }
        s += __shfl_xor(s, 1);
        s += __shfl_xor(s, 2);
        s += __shfl_xor(s, 4);
        s += __shfl_xor(s, 8);
        if (l15 == 0) atomicAdd(&scores[row], s);
      }
    }
  }
#undef DS_A
#undef DS_B
#undef MF
#undef BAR
#undef ST_A
#undef ST_B
}

// ---------------------------------------------------------------------------
// Kernel 2 (fallback, small-ws): fp32 reg-staged version (round-2, correct).
// ---------------------------------------------------------------------------
__global__ __launch_bounds__(256)
void scores_kernel_f32(const float* __restrict__ E, const float* __restrict__ Wk,
                       const float* __restrict__ query, const float* __restrict__ v,
                       float* __restrict__ scores) {
  const int bid = blockIdx.x;
  const int x  = bid & 7;
  const int ht = (bid >> 3) & 7;
  const int rt = x + ((bid >> 6) << 3);
  const int rowBase = rt * 128;
  const int hBase   = ht * 128;

  __shared__ short lA[128][72];
  __shared__ short lB[128][72];

  const int tid = threadIdx.x;
  const int lane = tid & 63;
  const int l15 = lane & 15;
  const int lhi = lane >> 4;
  const int wid = tid >> 6;
  const int wm = wid >> 1;
  const int wn = wid & 1;

  const int rq = tid >> 3;
  const int kq = (tid & 7) << 3;

  f32x4 acc[4][4] = {};

  for (int k0 = 0; k0 < NK; k0 += 64) {
    __syncthreads();
#pragma unroll
    for (int q = 0; q < 4; ++q) {
      int r = rq + q * 32;
      const float* pe = E  + (size_t)(rowBase + r) * NK + k0 + kq;
      const float* pw = Wk + (size_t)(hBase  + r) * NK + k0 + kq;
      float4 e0 = *(const float4*)(pe);
      float4 e1 = *(const float4*)(pe + 4);
      float4 w0 = *(const float4*)(pw);
      float4 w1 = *(const float4*)(pw + 4);
      bf16x8 se, sw;
      se[0] = f2bf(e0.x); se[1] = f2bf(e0.y); se[2] = f2bf(e0.z); se[3] = f2bf(e0.w);
      se[4] = f2bf(e1.x); se[5] = f2bf(e1.y); se[6] = f2bf(e1.z); se[7] = f2bf(e1.w);
      sw[0] = f2bf(w0.x); sw[1] = f2bf(w0.y); sw[2] = f2bf(w0.z); sw[3] = f2bf(w0.w);
      sw[4] = f2bf(w1.x); sw[5] = f2bf(w1.y); sw[6] = f2bf(w1.z); sw[7] = f2bf(w1.w);
      *(bf16x8*)&lA[r][kq] = se;
      *(bf16x8*)&lB[r][kq] = sw;
    }
    __syncthreads();

#pragma unroll
    for (int ks = 0; ks < 2; ++ks) {
      const int kk = ks * 32 + lhi * 8;
      bf16x8 af[4], bfr[4];
#pragma unroll
      for (int m = 0; m < 4; ++m)
        af[m] = *(const bf16x8*)&lA[wm * 64 + m * 16 + l15][kk];
#pragma unroll
      for (int n = 0; n < 4; ++n)
        bfr[n] = *(const bf16x8*)&lB[wn * 64 + n * 16 + l15][kk];
#pragma unroll
      for (int m = 0; m < 4; ++m)
#pragma unroll
        for (int n = 0; n < 4; ++n)
          acc[m][n] = __builtin_amdgcn_mfma_f32_16x16x32_bf16(af[m], bfr[n], acc[m][n], 0, 0, 0);
    }
  }

#pragma unroll
  for (int m = 0; m < 4; ++m) {
#pragma unroll
    for (int reg = 0; reg < 4; ++reg) {
      int row = rowBase + wm * 64 + m * 16 + lhi * 4 + reg;
      int b = row & (NB - 1);
      float s = 0.f;
#pragma unroll
      for (int n = 0; n < 4; ++n) {
        int col = hBase + wn * 64 + n * 16 + l15;
        float c = acc[m][n][reg];
        s += fast_tanh(c + query[b * NH + col]) * v[col];
      }
      s += __shfl_xor(s, 1);
      s += __shfl_xor(s, 2);
      s += __shfl_xor(s, 4);
      s += __shfl_xor(s, 8);
      if (l15 == 0) atomicAdd(&scores[row], s);
    }
  }
}

// ---------------------------------------------------------------------------
// Kernel 3: masked softmax over t, per b.  In-place scores -> alphas.
// ---------------------------------------------------------------------------
__global__ __launch_bounds__(256)
void softmax_kernel(const int* __restrict__ mask, float* __restrict__ alphas) {
  int b = blockIdx.x;
  int tid = threadIdx.x;
  float sv[8];
  int mv[8];
  float mx = -INFINITY;
#pragma unroll
  for (int i = 0; i < 8; ++i) {
    int t = tid + i * 256;
    sv[i] = alphas[t * NB + b];
    mv[i] = mask[t * NB + b];
    if (mv[i] != 0) mx = fmaxf(mx, sv[i]);
  }
  __shared__ float red[256];
  red[tid] = mx;
  __syncthreads();
  for (int o = 128; o > 0; o >>= 1) {
    if (tid < o) red[tid] = fmaxf(red[tid], red[tid + o]);
    __syncthreads();
  }
  mx = red[0];
  __syncthreads();
  float sum = 0.f;
#pragma unroll
  for (int i = 0; i < 8; ++i) {
    if (mv[i] != 0) { sv[i] = expf(sv[i] - mx); sum += sv[i]; }
    else sv[i] = 0.f;
  }
  red[tid] = sum;
  __syncthreads();
  for (int o = 128; o > 0; o >>= 1) {
    if (tid < o) red[tid] += red[tid + o];
    __syncthreads();
  }
  float inv = 1.f / red[0];
#pragma unroll
  for (int i = 0; i < 8; ++i) {
    int t = tid + i * 256;
    alphas[t * NB + b] = sv[i] * inv;
  }
}

// ---------------------------------------------------------------------------
// Kernel 4a (fast path): context[b][k] = sum_t alphas[t][b] * Ebf[t][b][k]
// bf16 E (halves HBM traffic vs fp32); un-swizzles the baked chunk layout.
// Each thread owns 2 adjacent k (same 16B chunk), ushort2 loads.
// ---------------------------------------------------------------------------
__global__ __launch_bounds__(256)
void context_bf16_kernel(const short* __restrict__ Ebf, const float* __restrict__ alphas,
                         float* __restrict__ ctx) {
  int k0 = (blockIdx.x * 256 + threadIdx.x) * 2;   // grid.x = NK/512
  int b  = blockIdx.y;
  int t0 = blockIdx.z * 64;
  const int slice = k0 & ~63;
  const int c = (k0 >> 3) & 7;
  const int e = k0 & 7;
  float a0 = 0.f, a1 = 0.f;
  for (int t = t0; t < t0 + 64; ++t) {
    long row = (long)t * NB + b;
    float al = alphas[t * NB + b];
    int ksw = slice | ((c ^ ((int)row & 7)) << 3) | e;
    ushort2 ev = *(const ushort2*)(Ebf + row * NK + ksw);
    a0 = fmaf(al, bf2f(ev.x), a0);
    a1 = fmaf(al, bf2f(ev.y), a1);
  }
  atomicAdd(&ctx[b * NK + k0], a0);
  atomicAdd(&ctx[b * NK + k0 + 1], a1);
}

// ---------------------------------------------------------------------------
// Kernel 4b (fallback): context from fp32 E.
// ---------------------------------------------------------------------------
__global__ __launch_bounds__(256)
void context_kernel(const float* __restrict__ E, const float* __restrict__ alphas,
                    float* __restrict__ ctx) {
  int k = blockIdx.x * 256 + threadIdx.x;
  int b = blockIdx.y;
  int t0 = blockIdx.z * 128;
  float acc = 0.f;
  for (int t = t0; t < t0 + 128; ++t) {
    float a = alphas[t * NB + b];
    acc = fmaf(a, E[((size_t)t * NB + b) * NK + k], acc);
  }
  atomicAdd(&ctx[b * NK + k], acc);
}

// ---------------------------------------------------------------------------
extern "C" void kernel_launch(void* const* d_in, const int* in_sizes, int n_in,
                              void* d_out, int out_size, void* d_ws, size_t ws_size,
                              hipStream_t stream) {
  const float* dec  = (const float*)d_in[0];
  const float* enc  = (const float*)d_in[1];
  const int*   mask = (const int*)d_in[2];
  const float* Wk   = (const float*)d_in[3];
  const float* Wq   = (const float*)d_in[4];
  const float* v    = (const float*)d_in[5];

  float* ctx    = (float*)d_out;
  float* alphas = (float*)d_out + NB * NK;

  const size_t QUERY_B = (size_t)NB * NH * sizeof(float);            // 128 KB
  const size_t WKBF_B  = (size_t)NH * NK * sizeof(short);            // 2 MB
  const size_t EBF_B   = (size_t)NTB * NK * sizeof(short);           // 128 MB
  float* query = (float*)d_ws;
  short* Wkbf  = (short*)((char*)d_ws + QUERY_B);
  short* Ebf   = (short*)((char*)d_ws + QUERY_B + WKBF_B);
  const bool fast = ws_size >= QUERY_B + WKBF_B + EBF_B;

  hipMemsetAsync(d_out, 0, (size_t)out_size * sizeof(float), stream);

  query_kernel<<<dim3(NB, NH / 64), 256, 0, stream>>>(dec, Wq, query);
  if (fast) {
    convert_swz_kernel<<<dim3(2048), 256, 0, stream>>>(enc, Ebf, (long)NTB * NK / 8);
    convert_swz_kernel<<<dim3(512), 256, 0, stream>>>(Wk, Wkbf, (long)NH * NK / 8);
    const int SMEM = 2 * 32768 * (int)sizeof(short);  // 128 KB
    hipFuncSetAttribute((const void*)scores_mfma_kernel,
                        hipFuncAttributeMaxDynamicSharedMemorySize, SMEM);
    scores_mfma_kernel<<<dim3((NTB / 256) * (NH / 256)), dim3(512), SMEM, stream>>>(
        Ebf, Wkbf, query, v, alphas);
    softmax_kernel<<<dim3(NB), 256, 0, stream>>>(mask, alphas);
    context_bf16_kernel<<<dim3(NK / 512, NB, NT / 64), 256, 0, stream>>>(
        Ebf, alphas, ctx);
  } else {
    scores_kernel_f32<<<dim3((NTB / 128) * (NH / 128)), 256, 0, stream>>>(
        enc, Wk, query, v, alphas);
    softmax_kernel<<<dim3(NB), 256, 0, stream>>>(mask, alphas);
    context_kernel<<<dim3(NK / 256, NB, NT / 128), 256, 0, stream>>>(enc, alphas, ctx);
  }
}

// Round 10
// 230.598 us; speedup vs baseline: 1.5564x; 1.3324x over previous
//
#include <hip/hip_runtime.h>
#include <stdint.h>

constexpr int NB = 32;    // batch
constexpr int NT = 2048;  // time
constexpr int NK = 1024;  // encoder hidden (K of GEMM)
constexpr int NH = 1024;  // attn hidden (N of GEMM)
constexpr int NQ = 1024;  // decoder hidden
constexpr int NTB = NT * NB;  // 65536 GEMM rows (before mask compaction)

typedef __attribute__((ext_vector_type(8))) short bf16x8;
typedef __attribute__((ext_vector_type(4))) float f32x4;

__device__ __forceinline__ short f2bf(float f) {
  union { float f; unsigned u; } c{f};
  unsigned r = (c.u + 0x7fffu + ((c.u >> 16) & 1u)) >> 16;
  return (short)r;
}
__device__ __forceinline__ float bf2f(unsigned short u) {
  union { unsigned u; float f; } c{(unsigned)u << 16};
  return c.f;
}

// tanh via hw exp: (e-1)/(e+1), e=exp(2x), clamped.  ~6 VALU ops.
__device__ __forceinline__ float fast_tanh(float x) {
  float e = __expf(fminf(fmaxf(x + x, -30.f), 30.f));
  return (e - 1.f) * __builtin_amdgcn_rcpf(e + 1.f);
}

__device__ __forceinline__ void gload16(const void* g, void* l) {
  __builtin_amdgcn_global_load_lds(
      (const __attribute__((address_space(1))) unsigned int*)g,
      (__attribute__((address_space(3))) unsigned int*)l, 16, 0, 0);
}

// ---------------------------------------------------------------------------
// Kernel S: mask compaction scan (deterministic, single block, 1024 thr).
// Produces rmap[compact] = orig row (t*NB+b), b-MAJOR order (b asc, t asc),
// meta[0] = nkeep, meta[1+b] = colstart[b] (b=0..32).  Pads rmap to a
// multiple of 128 with orig=0 (valid row; GEMM scatter is guarded).
// ---------------------------------------------------------------------------
__global__ __launch_bounds__(1024)
void scan_kernel(const int* __restrict__ mask, unsigned short* __restrict__ rmap,
                 int* __restrict__ meta) {
  __shared__ int part[1024];
  __shared__ int colbase[33];
  const int tid = threadIdx.x;
  const int b   = tid & 31;       // coalesced mask reads: consecutive tid -> consecutive b
  const int sub = tid >> 5;       // 0..31, each owns 64 t's
  const int p   = b * 32 + sub;   // scan order = (b, sub) lexicographic
  int cnt = 0;
  for (int i = 0; i < 64; ++i) cnt += (mask[(sub * 64 + i) * NB + b] != 0) ? 1 : 0;
  part[p] = cnt;
  __syncthreads();
  for (int off = 1; off < 1024; off <<= 1) {   // Hillis-Steele inclusive scan
    int vv = part[p];
    int add = (p >= off) ? part[p - off] : 0;
    __syncthreads();
    part[p] = vv + add;
    __syncthreads();
  }
  const int excl = part[p] - cnt;
  if (tid < 32) colbase[tid + 1] = part[tid * 32 + 31];
  if (tid == 0) colbase[0] = 0;
  int off = excl;
  for (int i = 0; i < 64; ++i) {
    int t = sub * 64 + i;
    if (mask[t * NB + b] != 0) rmap[off++] = (unsigned short)(t * NB + b);
  }
  __syncthreads();
  if (tid < 33) meta[1 + tid] = colbase[tid];
  if (tid == 0) {
    int total = colbase[32];
    meta[0] = total;
    int pad = (total + 127) & ~127;
    for (int j = total; j < pad; ++j) rmap[j] = 0;
  }
}

// ---------------------------------------------------------------------------
// Kernel 0a: dense fp32 -> bf16 convert WITH baked LDS bank-swizzle (Wk; and
// E in tier B).  Stored chunk c holds source chunk (c ^ (row&7)) within each
// 64-col slice; GEMM stages linearly and un-swizzles on ds_read (conflicts=0).
// ---------------------------------------------------------------------------
__global__ __launch_bounds__(256)
void convert_swz_kernel(const float* __restrict__ in, short* __restrict__ out,
                        long nchunks) {
  long stride = (long)gridDim.x * 256;
  for (long i = (long)blockIdx.x * 256 + threadIdx.x; i < nchunks; i += stride) {
    long r = i >> 7;
    int c = (int)(i & 127);
    int src = (c & ~7) | ((c & 7) ^ ((int)r & 7));
    const float* p = in + (r << 10) + (src << 3);
    float4 a = *(const float4*)p;
    float4 b = *(const float4*)(p + 4);
    bf16x8 o;
    o[0] = f2bf(a.x); o[1] = f2bf(a.y); o[2] = f2bf(a.z); o[3] = f2bf(a.w);
    o[4] = f2bf(b.x); o[5] = f2bf(b.y); o[6] = f2bf(b.z); o[7] = f2bf(b.w);
    *(bf16x8*)(out + (i << 3)) = o;
  }
}

// ---------------------------------------------------------------------------
// Kernel 0b (tier A): GATHER convert — only masked-in rows, via rmap.
// Ebf row cr = enc row rmap[cr], swizzle keyed on cr&7 (matches GEMM+context).
// ---------------------------------------------------------------------------
__global__ __launch_bounds__(256)
void convert_gather_kernel(const float* __restrict__ enc,
                           const unsigned short* __restrict__ rmap,
                           const int* __restrict__ meta, short* __restrict__ Ebf) {
  const int padN = (meta[0] + 127) & ~127;
  const long nch = (long)padN << 7;    // 128 chunks per row
  long stride = (long)gridDim.x * 256;
  for (long i = (long)blockIdx.x * 256 + threadIdx.x; i < nch; i += stride) {
    int cr = (int)(i >> 7);
    int c  = (int)(i & 127);
    int orig = rmap[cr];
    int srcc = (c & ~7) | ((c & 7) ^ (cr & 7));
    const float* p = enc + ((size_t)orig << 10) + (srcc << 3);
    float4 a = *(const float4*)p;
    float4 b = *(const float4*)(p + 4);
    bf16x8 o;
    o[0] = f2bf(a.x); o[1] = f2bf(a.y); o[2] = f2bf(a.z); o[3] = f2bf(a.w);
    o[4] = f2bf(b.x); o[5] = f2bf(b.y); o[6] = f2bf(b.z); o[7] = f2bf(b.w);
    *(bf16x8*)(Ebf + (i << 3)) = o;
  }
}

// ---------------------------------------------------------------------------
// Kernel 1: query[b][h] = sum_q dec[b][q] * Wq[h][q]  (fp32, tiny)
// Writes into the ctx region of d_out (re-zeroed before the context kernel).
// ---------------------------------------------------------------------------
__global__ __launch_bounds__(256)
void query_kernel(const float* __restrict__ dec, const float* __restrict__ Wq,
                  float* __restrict__ query) {
  int b = blockIdx.x;
  int h0 = blockIdx.y * 64;
  __shared__ float sdec[NQ];
  for (int i = threadIdx.x; i < NQ; i += 256) sdec[i] = dec[b * NQ + i];
  __syncthreads();
  int hl = threadIdx.x >> 2;
  int p  = threadIdx.x & 3;
  int h = h0 + hl;
  const float* wrow = Wq + (size_t)h * NQ;
  float s = 0.f;
  for (int k = p * 4; k < NQ; k += 16) {
    float4 w = *(const float4*)(wrow + k);
    float4 d = *(const float4*)(sdec + k);
    s += w.x * d.x + w.y * d.y + w.z * d.z + w.w * d.w;
  }
  s += __shfl_xor(s, 1);
  s += __shfl_xor(s, 2);
  if (p == 0) query[b * NH + h] = s;
}

// ---------------------------------------------------------------------------
// Kernel 2: r8-structure bf16-MFMA GEMM over COMPACTED rows + fused
// fast-tanh/v-dot epilogue.  128x128 tile, BK=64, 4 waves, single 32 KB LDS,
// 2 __syncthreads/iter, ~4 blocks/CU (r8-measured: 175us/782TF dense; here
// ~half the tiles are active).  Staging is DENSE in compact space (gather
// already done by convert); only the epilogue uses rmap (b lookup + scatter,
// guarded at crow<nkeep).  Blocks with rowBase>=pad(nkeep) exit early.
// ds_read un-swizzles chunk^(row&7): conflict-free (r4/r6/r8 verified).
// compacted==0 -> dense tier-B behavior (orig=crow, no guard).
// ---------------------------------------------------------------------------
__global__ __launch_bounds__(256, 4)
void scores_mfma_kernel(const short* __restrict__ Ebf, const short* __restrict__ Wkbf,
                        const float* __restrict__ query, const float* __restrict__ v,
                        float* __restrict__ scores,
                        const unsigned short* __restrict__ rmap,
                        const int* __restrict__ meta, const int compacted) {
  const int nkeep = compacted ? meta[0] : NTB;
  const int padN  = (nkeep + 127) & ~127;

  const int bid = blockIdx.x;
  const int x  = bid & 7;                  // XCD
  const int ht = (bid >> 3) & 7;           // NH/128 = 8, fast on XCD
  const int rt = ((bid >> 6) << 3) + x;    // 0..511
  const int rowBase = rt * 128;
  if (rowBase >= padN) return;             // uniform early exit (inactive tile)
  const int hBase = ht * 128;

  __shared__ short lA[128 * 64];  // 16 KB
  __shared__ short lB[128 * 64];  // 16 KB

  const int tid  = threadIdx.x;
  const int lane = tid & 63;
  const int l15  = lane & 15;
  const int lhi  = lane >> 4;
  const int wid  = tid >> 6;      // 0..3
  const int wm   = wid >> 1;      // 0..1
  const int wn   = wid & 1;       // 0..1

  const int srow = tid >> 3;      // 0..31 staging row within round
  const int sc   = tid & 7;       // staging chunk
  const int ldsOffS = tid << 3;   // shorts; dest = wave-uniform base + lane*16B

  f32x4 acc[4][4] = {};

  for (int t = 0; t < 16; ++t) {
    const int k0 = t << 6;
    const int src = k0 + (sc << 3);   // LINEAR: swizzle baked in Ebf/Wkbf
    __syncthreads();                  // prev iter's reads done before overwrite
#pragma unroll
    for (int q = 0; q < 4; ++q) {
      const int row = q * 32 + srow;
      gload16(Ebf  + (size_t)(rowBase + row) * NK + src, &lA[(q << 11) + ldsOffS]);
      gload16(Wkbf + (size_t)(hBase  + row) * NK + src, &lB[(q << 11) + ldsOffS]);
    }
    __syncthreads();                  // drains vmcnt -> tile visible

#pragma unroll
    for (int ks = 0; ks < 2; ++ks) {
      bf16x8 af[4], bg[4];
#pragma unroll
      for (int m = 0; m < 4; ++m) {
        const int row = wm * 64 + m * 16 + l15;
        const int ch = ((ks * 4 + lhi) ^ (row & 7)) << 3;
        af[m] = *(const bf16x8*)&lA[row * 64 + ch];
      }
#pragma unroll
      for (int n = 0; n < 4; ++n) {
        const int row = wn * 64 + n * 16 + l15;
        const int ch = ((ks * 4 + lhi) ^ (row & 7)) << 3;
        bg[n] = *(const bf16x8*)&lB[row * 64 + ch];
      }
#pragma unroll
      for (int m = 0; m < 4; ++m)
#pragma unroll
        for (int n = 0; n < 4; ++n)
          acc[m][n] = __builtin_amdgcn_mfma_f32_16x16x32_bf16(af[m], bg[n], acc[m][n], 0, 0, 0);
    }
  }

  // epilogue: fast-tanh + v-dot, shfl-reduce over 16 col-lanes, guarded scatter
  // C/D layout: col = lane&15, row = (lane>>4)*4 + reg  [m89-verified]
#pragma unroll
  for (int m = 0; m < 4; ++m) {
#pragma unroll
    for (int reg = 0; reg < 4; ++reg) {
      const int crow = rowBase + wm * 64 + m * 16 + lhi * 4 + reg;
      const int orig = compacted ? (int)rmap[crow] : crow;
      const int b = orig & (NB - 1);
      float s = 0.f;
#pragma unroll
      for (int n = 0; n < 4; ++n) {
        int col = hBase + wn * 64 + n * 16 + l15;
        float c = acc[m][n][reg];
        s += fast_tanh(c + query[b * NH + col]) * v[col];
      }
      s += __shfl_xor(s, 1);
      s += __shfl_xor(s, 2);
      s += __shfl_xor(s, 4);
      s += __shfl_xor(s, 8);
      if (l15 == 0 && crow < nkeep) atomicAdd(&scores[orig], s);
    }
  }
}

// ---------------------------------------------------------------------------
// Kernel 2 (fallback, tier C): fp32 reg-staged version.
// ---------------------------------------------------------------------------
__global__ __launch_bounds__(256)
void scores_kernel_f32(const float* __restrict__ E, const float* __restrict__ Wk,
                       const float* __restrict__ query, const float* __restrict__ v,
                       float* __restrict__ scores) {
  const int bid = blockIdx.x;
  const int x  = bid & 7;
  const int ht = (bid >> 3) & 7;
  const int rt = x + ((bid >> 6) << 3);
  const int rowBase = rt * 128;
  const int hBase   = ht * 128;

  __shared__ short lA[128][72];
  __shared__ short lB[128][72];

  const int tid = threadIdx.x;
  const int lane = tid & 63;
  const int l15 = lane & 15;
  const int lhi = lane >> 4;
  const int wid = tid >> 6;
  const int wm = wid >> 1;
  const int wn = wid & 1;

  const int rq = tid >> 3;
  const int kq = (tid & 7) << 3;

  f32x4 acc[4][4] = {};

  for (int k0 = 0; k0 < NK; k0 += 64) {
    __syncthreads();
#pragma unroll
    for (int q = 0; q < 4; ++q) {
      int r = rq + q * 32;
      const float* pe = E  + (size_t)(rowBase + r) * NK + k0 + kq;
      const float* pw = Wk + (size_t)(hBase  + r) * NK + k0 + kq;
      float4 e0 = *(const float4*)(pe);
      float4 e1 = *(const float4*)(pe + 4);
      float4 w0 = *(const float4*)(pw);
      float4 w1 = *(const float4*)(pw + 4);
      bf16x8 se, sw;
      se[0] = f2bf(e0.x); se[1] = f2bf(e0.y); se[2] = f2bf(e0.z); se[3] = f2bf(e0.w);
      se[4] = f2bf(e1.x); se[5] = f2bf(e1.y); se[6] = f2bf(e1.z); se[7] = f2bf(e1.w);
      sw[0] = f2bf(w0.x); sw[1] = f2bf(w0.y); sw[2] = f2bf(w0.z); sw[3] = f2bf(w0.w);
      sw[4] = f2bf(w1.x); sw[5] = f2bf(w1.y); sw[6] = f2bf(w1.z); sw[7] = f2bf(w1.w);
      *(bf16x8*)&lA[r][kq] = se;
      *(bf16x8*)&lB[r][kq] = sw;
    }
    __syncthreads();

#pragma unroll
    for (int ks = 0; ks < 2; ++ks) {
      const int kk = ks * 32 + lhi * 8;
      bf16x8 af[4], bfr[4];
#pragma unroll
      for (int m = 0; m < 4; ++m)
        af[m] = *(const bf16x8*)&lA[wm * 64 + m * 16 + l15][kk];
#pragma unroll
      for (int n = 0; n < 4; ++n)
        bfr[n] = *(const bf16x8*)&lB[wn * 64 + n * 16 + l15][kk];
#pragma unroll
      for (int m = 0; m < 4; ++m)
#pragma unroll
        for (int n = 0; n < 4; ++n)
          acc[m][n] = __builtin_amdgcn_mfma_f32_16x16x32_bf16(af[m], bfr[n], acc[m][n], 0, 0, 0);
    }
  }

#pragma unroll
  for (int m = 0; m < 4; ++m) {
#pragma unroll
    for (int reg = 0; reg < 4; ++reg) {
      int row = rowBase + wm * 64 + m * 16 + lhi * 4 + reg;
      int b = row & (NB - 1);
      float s = 0.f;
#pragma unroll
      for (int n = 0; n < 4; ++n) {
        int col = hBase + wn * 64 + n * 16 + l15;
        float c = acc[m][n][reg];
        s += fast_tanh(c + query[b * NH + col]) * v[col];
      }
      s += __shfl_xor(s, 1);
      s += __shfl_xor(s, 2);
      s += __shfl_xor(s, 4);
      s += __shfl_xor(s, 8);
      if (l15 == 0) atomicAdd(&scores[row], s);
    }
  }
}

// ---------------------------------------------------------------------------
// Kernel 3: masked softmax over t, per b.  In-place scores -> alphas.
// ---------------------------------------------------------------------------
__global__ __launch_bounds__(256)
void softmax_kernel(const int* __restrict__ mask, float* __restrict__ alphas) {
  int b = blockIdx.x;
  int tid = threadIdx.x;
  float sv[8];
  int mv[8];
  float mx = -INFINITY;
#pragma unroll
  for (int i = 0; i < 8; ++i) {
    int t = tid + i * 256;
    sv[i] = alphas[t * NB + b];
    mv[i] = mask[t * NB + b];
    if (mv[i] != 0) mx = fmaxf(mx, sv[i]);
  }
  __shared__ float red[256];
  red[tid] = mx;
  __syncthreads();
  for (int o = 128; o > 0; o >>= 1) {
    if (tid < o) red[tid] = fmaxf(red[tid], red[tid + o]);
    __syncthreads();
  }
  mx = red[0];
  __syncthreads();
  float sum = 0.f;
#pragma unroll
  for (int i = 0; i < 8; ++i) {
    if (mv[i] != 0) { sv[i] = expf(sv[i] - mx); sum += sv[i]; }
    else sv[i] = 0.f;
  }
  red[tid] = sum;
  __syncthreads();
  for (int o = 128; o > 0; o >>= 1) {
    if (tid < o) red[tid] += red[tid + o];
    __syncthreads();
  }
  float inv = 1.f / red[0];
#pragma unroll
  for (int i = 0; i < 8; ++i) {
    int t = tid + i * 256;
    alphas[t * NB + b] = sv[i] * inv;
  }
}

// ---------------------------------------------------------------------------
// Kernel 4a (tier A): context over per-b contiguous COMPACT ranges of Ebf.
// ctx[b][k] = sum_{cr in [cs[b],cs[b+1])} alphas[rmap[cr]] * Ebf[cr][k]
// Dense bf16 reads (un-swizzled on the fly); 2 k per thread.
// ---------------------------------------------------------------------------
__global__ __launch_bounds__(256)
void context_cbf16_kernel(const short* __restrict__ Ebf,
                          const unsigned short* __restrict__ rmap,
                          const int* __restrict__ meta,
                          const float* __restrict__ alphas, float* __restrict__ ctx) {
  const int b = blockIdx.y;
  const int cs0 = meta[1 + b], cs1 = meta[2 + b];
  int start = cs0 + blockIdx.z * 64;
  if (start >= cs1) return;
  int end = min(start + 64, cs1);
  int k0 = (blockIdx.x * 256 + threadIdx.x) * 2;
  const int slice = k0 & ~63;
  const int c = (k0 >> 3) & 7;
  const int e = k0 & 7;
  float a0 = 0.f, a1 = 0.f;
  for (int cr = start; cr < end; ++cr) {
    float al = alphas[rmap[cr]];
    int ksw = slice | ((c ^ (cr & 7)) << 3) | e;
    ushort2 ev = *(const ushort2*)(Ebf + ((size_t)cr << 10) + ksw);
    a0 = fmaf(al, bf2f(ev.x), a0);
    a1 = fmaf(al, bf2f(ev.y), a1);
  }
  atomicAdd(&ctx[b * NK + k0], a0);
  atomicAdd(&ctx[b * NK + k0 + 1], a1);
}

// ---------------------------------------------------------------------------
// Kernel 4b (tiers B/C): masked fp32 context from enc (skips alpha==0 rows).
// ---------------------------------------------------------------------------
__global__ __launch_bounds__(256)
void context_f32m_kernel(const float* __restrict__ E, const float* __restrict__ alphas,
                         float* __restrict__ ctx) {
  int k = blockIdx.x * 256 + threadIdx.x;
  int b = blockIdx.y;
  int t0 = blockIdx.z * 128;
  float acc = 0.f;
  for (int t = t0; t < t0 + 128; ++t) {
    float a = alphas[t * NB + b];
    if (a != 0.f) acc = fmaf(a, E[((size_t)t * NB + b) * NK + k], acc);
  }
  atomicAdd(&ctx[b * NK + k], acc);
}

// ---------------------------------------------------------------------------
extern "C" void kernel_launch(void* const* d_in, const int* in_sizes, int n_in,
                              void* d_out, int out_size, void* d_ws, size_t ws_size,
                              hipStream_t stream) {
  const float* dec  = (const float*)d_in[0];
  const float* enc  = (const float*)d_in[1];
  const int*   mask = (const int*)d_in[2];
  const float* Wk   = (const float*)d_in[3];
  const float* Wq   = (const float*)d_in[4];
  const float* v    = (const float*)d_in[5];

  float* ctx    = (float*)d_out;              // B*K; doubles as query buffer
  float* alphas = (float*)d_out + NB * NK;    // T*B (scores first)
  float* query  = ctx;                        // B*H == B*K floats, exact fit

  // workspace layout
  const size_t WKBF_B = (size_t)NH * NK * sizeof(short);     // 2 MiB
  const size_t META_B = 256;
  const size_t RMAP_B = (size_t)(NTB + 128) * sizeof(unsigned short);
  const size_t EBF_B  = (size_t)NTB * NK * sizeof(short);    // 128 MiB worst case
  short*          Wkbf = (short*)d_ws;
  int*            meta = (int*)((char*)d_ws + WKBF_B);
  unsigned short* rmap = (unsigned short*)((char*)d_ws + WKBF_B + META_B);
  short*          Ebf  = (short*)((char*)d_ws + WKBF_B + META_B + RMAP_B);
  short*          EbfB = (short*)((char*)d_ws + WKBF_B);     // tier-B layout
  const bool tierA = ws_size >= WKBF_B + META_B + RMAP_B + EBF_B;
  const bool tierB = ws_size >= WKBF_B + EBF_B;

  hipMemsetAsync(d_out, 0, (size_t)out_size * sizeof(float), stream);
  query_kernel<<<dim3(NB, NH / 64), 256, 0, stream>>>(dec, Wq, query);

  if (tierA) {
    scan_kernel<<<dim3(1), 1024, 0, stream>>>(mask, rmap, meta);
    convert_swz_kernel<<<dim3(512), 256, 0, stream>>>(Wk, Wkbf, (long)NH * NK / 8);
    convert_gather_kernel<<<dim3(1024), 256, 0, stream>>>(enc, rmap, meta, Ebf);
    scores_mfma_kernel<<<dim3((NTB / 128) * (NH / 128)), 256, 0, stream>>>(
        Ebf, Wkbf, query, v, alphas, rmap, meta, 1);
  } else if (tierB) {
    convert_swz_kernel<<<dim3(512), 256, 0, stream>>>(Wk, Wkbf, (long)NH * NK / 8);
    convert_swz_kernel<<<dim3(2048), 256, 0, stream>>>(enc, EbfB, (long)NTB * NK / 8);
    scores_mfma_kernel<<<dim3((NTB / 128) * (NH / 128)), 256, 0, stream>>>(
        EbfB, Wkbf, query, v, alphas, nullptr, nullptr, 0);
  } else {
    scores_kernel_f32<<<dim3((NTB / 128) * (NH / 128)), 256, 0, stream>>>(
        enc, Wk, query, v, alphas);
  }

  softmax_kernel<<<dim3(NB), 256, 0, stream>>>(mask, alphas);
  // query's buffer becomes ctx: re-zero before accumulation
  hipMemsetAsync(ctx, 0, (size_t)NB * NK * sizeof(float), stream);
  if (tierA) {
    context_cbf16_kernel<<<dim3(NK / 512, NB, 32), 256, 0, stream>>>(
        Ebf, rmap, meta, alphas, ctx);
  } else {
    context_f32m_kernel<<<dim3(NK / 256, NB, NT / 128), 256, 0, stream>>>(
        enc, alphas, ctx);
  }
}

// Round 11
// 225.011 us; speedup vs baseline: 1.5950x; 1.0248x over previous
//
#include <hip/hip_runtime.h>
#include <stdint.h>

constexpr int NB = 32;    // batch
constexpr int NT = 2048;  // time
constexpr int NK = 1024;  // encoder hidden (K of GEMM)
constexpr int NH = 1024;  // attn hidden (N of GEMM)
constexpr int NQ = 1024;  // decoder hidden
constexpr int NTB = NT * NB;  // 65536 GEMM rows (before mask compaction)

typedef __attribute__((ext_vector_type(8))) short bf16x8;
typedef __attribute__((ext_vector_type(4))) float f32x4;

__device__ __forceinline__ short f2bf(float f) {
  union { float f; unsigned u; } c{f};
  unsigned r = (c.u + 0x7fffu + ((c.u >> 16) & 1u)) >> 16;
  return (short)r;
}
__device__ __forceinline__ float bf2f(unsigned short u) {
  union { unsigned u; float f; } c{(unsigned)u << 16};
  return c.f;
}

// tanh via hw exp: (e-1)/(e+1), e=exp(2x), clamped.  ~6 VALU ops.
__device__ __forceinline__ float fast_tanh(float x) {
  float e = __expf(fminf(fmaxf(x + x, -30.f), 30.f));
  return (e - 1.f) * __builtin_amdgcn_rcpf(e + 1.f);
}

__device__ __forceinline__ void gload16(const void* g, void* l) {
  __builtin_amdgcn_global_load_lds(
      (const __attribute__((address_space(1))) unsigned int*)g,
      (__attribute__((address_space(3))) unsigned int*)l, 16, 0, 0);
}

// ---------------------------------------------------------------------------
// Kernel S: mask compaction scan (deterministic, single block, 1024 thr).
// rmap[compact] = orig row (t*NB+b), b-MAJOR order; meta[0]=nkeep,
// meta[1+b]=colstart[b] (b=0..32).  Pads rmap to x128 with row 0 (guarded).
// ---------------------------------------------------------------------------
__global__ __launch_bounds__(1024)
void scan_kernel(const int* __restrict__ mask, unsigned short* __restrict__ rmap,
                 int* __restrict__ meta) {
  __shared__ int part[1024];
  __shared__ int colbase[33];
  const int tid = threadIdx.x;
  const int b   = tid & 31;       // coalesced: consecutive tid -> consecutive b
  const int sub = tid >> 5;       // 0..31, each owns 64 t's
  const int p   = b * 32 + sub;   // scan order = (b, sub) lexicographic
  int cnt = 0;
  for (int i = 0; i < 64; ++i) cnt += (mask[(sub * 64 + i) * NB + b] != 0) ? 1 : 0;
  part[p] = cnt;
  __syncthreads();
  for (int off = 1; off < 1024; off <<= 1) {   // Hillis-Steele inclusive scan
    int vv = part[p];
    int add = (p >= off) ? part[p - off] : 0;
    __syncthreads();
    part[p] = vv + add;
    __syncthreads();
  }
  const int excl = part[p] - cnt;
  if (tid < 32) colbase[tid + 1] = part[tid * 32 + 31];
  if (tid == 0) colbase[0] = 0;
  int off = excl;
  for (int i = 0; i < 64; ++i) {
    int t = sub * 64 + i;
    if (mask[t * NB + b] != 0) rmap[off++] = (unsigned short)(t * NB + b);
  }
  __syncthreads();
  if (tid < 33) meta[1 + tid] = colbase[tid];
  if (tid == 0) {
    int total = colbase[32];
    meta[0] = total;
    int pad = (total + 127) & ~127;
    for (int j = total; j < pad; ++j) rmap[j] = 0;
  }
}

// ---------------------------------------------------------------------------
// Kernel P: fused prep — blocks [0,512): query[b][h] tiles; blocks
// [512,1024): Wk fp32->bf16 convert with baked swizzle.  Both 256 thr.
// ---------------------------------------------------------------------------
__global__ __launch_bounds__(256)
void prep_kernel(const float* __restrict__ dec, const float* __restrict__ Wq,
                 float* __restrict__ query,
                 const float* __restrict__ Wk, short* __restrict__ Wkbf) {
  const int bid = blockIdx.x;
  if (bid < 512) {
    // ---- query: b = bid&31, h-tile = bid>>5 ----
    const int b  = bid & 31;
    const int h0 = (bid >> 5) * 64;
    __shared__ float sdec[NQ];
    for (int i = threadIdx.x; i < NQ; i += 256) sdec[i] = dec[b * NQ + i];
    __syncthreads();
    int hl = threadIdx.x >> 2;
    int p  = threadIdx.x & 3;
    int h = h0 + hl;
    const float* wrow = Wq + (size_t)h * NQ;
    float s = 0.f;
    for (int k = p * 4; k < NQ; k += 16) {
      float4 w = *(const float4*)(wrow + k);
      float4 d = *(const float4*)(sdec + k);
      s += w.x * d.x + w.y * d.y + w.z * d.z + w.w * d.w;
    }
    s += __shfl_xor(s, 1);
    s += __shfl_xor(s, 2);
    if (p == 0) query[b * NH + h] = s;
  } else {
    // ---- Wk convert+swizzle: 512 blocks cover 131072 chunks in one pass ----
    const long i = (long)(bid - 512) * 256 + threadIdx.x;   // < 131072
    const long r = i >> 7;
    const int c  = (int)(i & 127);
    const int src = (c & ~7) | ((c & 7) ^ ((int)r & 7));
    const float* p = Wk + (r << 10) + (src << 3);
    float4 a = *(const float4*)p;
    float4 b2 = *(const float4*)(p + 4);
    bf16x8 o;
    o[0] = f2bf(a.x);  o[1] = f2bf(a.y);  o[2] = f2bf(a.z);  o[3] = f2bf(a.w);
    o[4] = f2bf(b2.x); o[5] = f2bf(b2.y); o[6] = f2bf(b2.z); o[7] = f2bf(b2.w);
    *(bf16x8*)(Wkbf + (i << 3)) = o;
  }
}

// ---------------------------------------------------------------------------
// Kernel 0a: dense fp32 -> bf16 convert WITH baked swizzle (tier B enc).
// ---------------------------------------------------------------------------
__global__ __launch_bounds__(256)
void convert_swz_kernel(const float* __restrict__ in, short* __restrict__ out,
                        long nchunks) {
  long stride = (long)gridDim.x * 256;
  for (long i = (long)blockIdx.x * 256 + threadIdx.x; i < nchunks; i += stride) {
    long r = i >> 7;
    int c = (int)(i & 127);
    int src = (c & ~7) | ((c & 7) ^ ((int)r & 7));
    const float* p = in + (r << 10) + (src << 3);
    float4 a = *(const float4*)p;
    float4 b = *(const float4*)(p + 4);
    bf16x8 o;
    o[0] = f2bf(a.x); o[1] = f2bf(a.y); o[2] = f2bf(a.z); o[3] = f2bf(a.w);
    o[4] = f2bf(b.x); o[5] = f2bf(b.y); o[6] = f2bf(b.z); o[7] = f2bf(b.w);
    *(bf16x8*)(out + (i << 3)) = o;
  }
}

// ---------------------------------------------------------------------------
// Kernel 0b (tier A): GATHER convert — only masked-in rows, via rmap.
// Ebf row cr = enc row rmap[cr], swizzle keyed on cr&7 (matches GEMM+context).
// ---------------------------------------------------------------------------
__global__ __launch_bounds__(256)
void convert_gather_kernel(const float* __restrict__ enc,
                           const unsigned short* __restrict__ rmap,
                           const int* __restrict__ meta, short* __restrict__ Ebf) {
  const int padN = (meta[0] + 127) & ~127;
  const long nch = (long)padN << 7;    // 128 chunks per row
  long stride = (long)gridDim.x * 256;
  for (long i = (long)blockIdx.x * 256 + threadIdx.x; i < nch; i += stride) {
    int cr = (int)(i >> 7);
    int c  = (int)(i & 127);
    int orig = rmap[cr];
    int srcc = (c & ~7) | ((c & 7) ^ (cr & 7));
    const float* p = enc + ((size_t)orig << 10) + (srcc << 3);
    float4 a = *(const float4*)p;
    float4 b = *(const float4*)(p + 4);
    bf16x8 o;
    o[0] = f2bf(a.x); o[1] = f2bf(a.y); o[2] = f2bf(a.z); o[3] = f2bf(a.w);
    o[4] = f2bf(b.x); o[5] = f2bf(b.y); o[6] = f2bf(b.z); o[7] = f2bf(b.w);
    *(bf16x8*)(Ebf + (i << 3)) = o;
  }
}

// ---------------------------------------------------------------------------
// Kernel 2: r8-structure bf16-MFMA GEMM over COMPACTED rows + fused
// fast-tanh/v-dot epilogue.  128x128 tile, BK=64, 4 waves, single 32 KB LDS,
// 2 __syncthreads/iter, ~4 blocks/CU (r8: 782 TF dense, conflicts 0).
// Dense staging in compact space; rmap only in epilogue (guarded scatter).
// Blocks with rowBase >= pad(nkeep) exit early.  compacted==0 -> dense.
// ---------------------------------------------------------------------------
__global__ __launch_bounds__(256, 4)
void scores_mfma_kernel(const short* __restrict__ Ebf, const short* __restrict__ Wkbf,
                        const float* __restrict__ query, const float* __restrict__ v,
                        float* __restrict__ scores,
                        const unsigned short* __restrict__ rmap,
                        const int* __restrict__ meta, const int compacted) {
  const int nkeep = compacted ? meta[0] : NTB;
  const int padN  = (nkeep + 127) & ~127;

  const int bid = blockIdx.x;
  const int x  = bid & 7;                  // XCD
  const int ht = (bid >> 3) & 7;           // NH/128 = 8, fast on XCD
  const int rt = ((bid >> 6) << 3) + x;    // 0..511
  const int rowBase = rt * 128;
  if (rowBase >= padN) return;             // uniform early exit (inactive tile)
  const int hBase = ht * 128;

  __shared__ short lA[128 * 64];  // 16 KB
  __shared__ short lB[128 * 64];  // 16 KB

  const int tid  = threadIdx.x;
  const int lane = tid & 63;
  const int l15  = lane & 15;
  const int lhi  = lane >> 4;
  const int wid  = tid >> 6;      // 0..3
  const int wm   = wid >> 1;      // 0..1
  const int wn   = wid & 1;       // 0..1

  const int sc   = tid & 7;       // staging chunk
  const int srow = tid >> 3;      // 0..31 staging row within round
  const int ldsOffS = tid << 3;   // shorts; dest = wave-uniform base + lane*16B

  f32x4 acc[4][4] = {};

  for (int t = 0; t < 16; ++t) {
    const int k0 = t << 6;
    const int src = k0 + (sc << 3);   // LINEAR: swizzle baked in Ebf/Wkbf
    __syncthreads();                  // prev iter's reads done before overwrite
#pragma unroll
    for (int q = 0; q < 4; ++q) {
      const int row = q * 32 + srow;
      gload16(Ebf  + (size_t)(rowBase + row) * NK + src, &lA[(q << 11) + ldsOffS]);
      gload16(Wkbf + (size_t)(hBase  + row) * NK + src, &lB[(q << 11) + ldsOffS]);
    }
    __syncthreads();                  // drains vmcnt -> tile visible

#pragma unroll
    for (int ks = 0; ks < 2; ++ks) {
      bf16x8 af[4], bg[4];
#pragma unroll
      for (int m = 0; m < 4; ++m) {
        const int row = wm * 64 + m * 16 + l15;
        const int ch = ((ks * 4 + lhi) ^ (row & 7)) << 3;
        af[m] = *(const bf16x8*)&lA[row * 64 + ch];
      }
#pragma unroll
      for (int n = 0; n < 4; ++n) {
        const int row = wn * 64 + n * 16 + l15;
        const int ch = ((ks * 4 + lhi) ^ (row & 7)) << 3;
        bg[n] = *(const bf16x8*)&lB[row * 64 + ch];
      }
#pragma unroll
      for (int m = 0; m < 4; ++m)
#pragma unroll
        for (int n = 0; n < 4; ++n)
          acc[m][n] = __builtin_amdgcn_mfma_f32_16x16x32_bf16(af[m], bg[n], acc[m][n], 0, 0, 0);
    }
  }

  // epilogue: fast-tanh + v-dot, shfl-reduce over 16 col-lanes, guarded scatter
  // C/D layout: col = lane&15, row = (lane>>4)*4 + reg  [m89-verified]
#pragma unroll
  for (int m = 0; m < 4; ++m) {
#pragma unroll
    for (int reg = 0; reg < 4; ++reg) {
      const int crow = rowBase + wm * 64 + m * 16 + lhi * 4 + reg;
      const int orig = compacted ? (int)rmap[crow] : crow;
      const int b = orig & (NB - 1);
      float s = 0.f;
#pragma unroll
      for (int n = 0; n < 4; ++n) {
        int col = hBase + wn * 64 + n * 16 + l15;
        float c = acc[m][n][reg];
        s += fast_tanh(c + query[b * NH + col]) * v[col];
      }
      s += __shfl_xor(s, 1);
      s += __shfl_xor(s, 2);
      s += __shfl_xor(s, 4);
      s += __shfl_xor(s, 8);
      if (l15 == 0 && crow < nkeep) atomicAdd(&scores[orig], s);
    }
  }
}

// ---------------------------------------------------------------------------
// Kernel 2 (fallback, tier C): fp32 reg-staged version.
// ---------------------------------------------------------------------------
__global__ __launch_bounds__(256)
void scores_kernel_f32(const float* __restrict__ E, const float* __restrict__ Wk,
                       const float* __restrict__ query, const float* __restrict__ v,
                       float* __restrict__ scores) {
  const int bid = blockIdx.x;
  const int x  = bid & 7;
  const int ht = (bid >> 3) & 7;
  const int rt = x + ((bid >> 6) << 3);
  const int rowBase = rt * 128;
  const int hBase   = ht * 128;

  __shared__ short lA[128][72];
  __shared__ short lB[128][72];

  const int tid = threadIdx.x;
  const int lane = tid & 63;
  const int l15 = lane & 15;
  const int lhi = lane >> 4;
  const int wid = tid >> 6;
  const int wm = wid >> 1;
  const int wn = wid & 1;

  const int rq = tid >> 3;
  const int kq = (tid & 7) << 3;

  f32x4 acc[4][4] = {};

  for (int k0 = 0; k0 < NK; k0 += 64) {
    __syncthreads();
#pragma unroll
    for (int q = 0; q < 4; ++q) {
      int r = rq + q * 32;
      const float* pe = E  + (size_t)(rowBase + r) * NK + k0 + kq;
      const float* pw = Wk + (size_t)(hBase  + r) * NK + k0 + kq;
      float4 e0 = *(const float4*)(pe);
      float4 e1 = *(const float4*)(pe + 4);
      float4 w0 = *(const float4*)(pw);
      float4 w1 = *(const float4*)(pw + 4);
      bf16x8 se, sw;
      se[0] = f2bf(e0.x); se[1] = f2bf(e0.y); se[2] = f2bf(e0.z); se[3] = f2bf(e0.w);
      se[4] = f2bf(e1.x); se[5] = f2bf(e1.y); se[6] = f2bf(e1.z); se[7] = f2bf(e1.w);
      sw[0] = f2bf(w0.x); sw[1] = f2bf(w0.y); sw[2] = f2bf(w0.z); sw[3] = f2bf(w0.w);
      sw[4] = f2bf(w1.x); sw[5] = f2bf(w1.y); sw[6] = f2bf(w1.z); sw[7] = f2bf(w1.w);
      *(bf16x8*)&lA[r][kq] = se;
      *(bf16x8*)&lB[r][kq] = sw;
    }
    __syncthreads();

#pragma unroll
    for (int ks = 0; ks < 2; ++ks) {
      const int kk = ks * 32 + lhi * 8;
      bf16x8 af[4], bfr[4];
#pragma unroll
      for (int m = 0; m < 4; ++m)
        af[m] = *(const bf16x8*)&lA[wm * 64 + m * 16 + l15][kk];
#pragma unroll
      for (int n = 0; n < 4; ++n)
        bfr[n] = *(const bf16x8*)&lB[wn * 64 + n * 16 + l15][kk];
#pragma unroll
      for (int m = 0; m < 4; ++m)
#pragma unroll
        for (int n = 0; n < 4; ++n)
          acc[m][n] = __builtin_amdgcn_mfma_f32_16x16x32_bf16(af[m], bfr[n], acc[m][n], 0, 0, 0);
    }
  }

#pragma unroll
  for (int m = 0; m < 4; ++m) {
#pragma unroll
    for (int reg = 0; reg < 4; ++reg) {
      int row = rowBase + wm * 64 + m * 16 + lhi * 4 + reg;
      int b = row & (NB - 1);
      float s = 0.f;
#pragma unroll
      for (int n = 0; n < 4; ++n) {
        int col = hBase + wn * 64 + n * 16 + l15;
        float c = acc[m][n][reg];
        s += fast_tanh(c + query[b * NH + col]) * v[col];
      }
      s += __shfl_xor(s, 1);
      s += __shfl_xor(s, 2);
      s += __shfl_xor(s, 4);
      s += __shfl_xor(s, 8);
      if (l15 == 0) atomicAdd(&scores[row], s);
    }
  }
}

// ---------------------------------------------------------------------------
// Kernel 3: masked softmax over t, per b.  In-place scores -> alphas.
// ---------------------------------------------------------------------------
__global__ __launch_bounds__(256)
void softmax_kernel(const int* __restrict__ mask, float* __restrict__ alphas) {
  int b = blockIdx.x;
  int tid = threadIdx.x;
  float sv[8];
  int mv[8];
  float mx = -INFINITY;
#pragma unroll
  for (int i = 0; i < 8; ++i) {
    int t = tid + i * 256;
    sv[i] = alphas[t * NB + b];
    mv[i] = mask[t * NB + b];
    if (mv[i] != 0) mx = fmaxf(mx, sv[i]);
  }
  __shared__ float red[256];
  red[tid] = mx;
  __syncthreads();
  for (int o = 128; o > 0; o >>= 1) {
    if (tid < o) red[tid] = fmaxf(red[tid], red[tid + o]);
    __syncthreads();
  }
  mx = red[0];
  __syncthreads();
  float sum = 0.f;
#pragma unroll
  for (int i = 0; i < 8; ++i) {
    if (mv[i] != 0) { sv[i] = expf(sv[i] - mx); sum += sv[i]; }
    else sv[i] = 0.f;
  }
  red[tid] = sum;
  __syncthreads();
  for (int o = 128; o > 0; o >>= 1) {
    if (tid < o) red[tid] += red[tid + o];
    __syncthreads();
  }
  float inv = 1.f / red[0];
#pragma unroll
  for (int i = 0; i < 8; ++i) {
    int t = tid + i * 256;
    alphas[t * NB + b] = sv[i] * inv;
  }
}

// ---------------------------------------------------------------------------
// Kernel 4a (tier A): context over per-b contiguous COMPACT ranges of Ebf.
// ---------------------------------------------------------------------------
__global__ __launch_bounds__(256)
void context_cbf16_kernel(const short* __restrict__ Ebf,
                          const unsigned short* __restrict__ rmap,
                          const int* __restrict__ meta,
                          const float* __restrict__ alphas, float* __restrict__ ctx) {
  const int b = blockIdx.y;
  const int cs0 = meta[1 + b], cs1 = meta[2 + b];
  int start = cs0 + blockIdx.z * 64;
  if (start >= cs1) return;
  int end = min(start + 64, cs1);
  int k0 = (blockIdx.x * 256 + threadIdx.x) * 2;
  const int slice = k0 & ~63;
  const int c = (k0 >> 3) & 7;
  const int e = k0 & 7;
  float a0 = 0.f, a1 = 0.f;
  for (int cr = start; cr < end; ++cr) {
    float al = alphas[rmap[cr]];
    int ksw = slice | ((c ^ (cr & 7)) << 3) | e;
    ushort2 ev = *(const ushort2*)(Ebf + ((size_t)cr << 10) + ksw);
    a0 = fmaf(al, bf2f(ev.x), a0);
    a1 = fmaf(al, bf2f(ev.y), a1);
  }
  atomicAdd(&ctx[b * NK + k0], a0);
  atomicAdd(&ctx[b * NK + k0 + 1], a1);
}

// ---------------------------------------------------------------------------
// Kernel 4b (tiers B/C): masked fp32 context from enc (skips alpha==0 rows).
// ---------------------------------------------------------------------------
__global__ __launch_bounds__(256)
void context_f32m_kernel(const float* __restrict__ E, const float* __restrict__ alphas,
                         float* __restrict__ ctx) {
  int k = blockIdx.x * 256 + threadIdx.x;
  int b = blockIdx.y;
  int t0 = blockIdx.z * 128;
  float acc = 0.f;
  for (int t = t0; t < t0 + 128; ++t) {
    float a = alphas[t * NB + b];
    if (a != 0.f) acc = fmaf(a, E[((size_t)t * NB + b) * NK + k], acc);
  }
  atomicAdd(&ctx[b * NK + k], acc);
}

// ---------------------------------------------------------------------------
extern "C" void kernel_launch(void* const* d_in, const int* in_sizes, int n_in,
                              void* d_out, int out_size, void* d_ws, size_t ws_size,
                              hipStream_t stream) {
  const float* dec  = (const float*)d_in[0];
  const float* enc  = (const float*)d_in[1];
  const int*   mask = (const int*)d_in[2];
  const float* Wk   = (const float*)d_in[3];
  const float* Wq   = (const float*)d_in[4];
  const float* v    = (const float*)d_in[5];

  float* ctx    = (float*)d_out;              // B*K
  float* alphas = (float*)d_out + NB * NK;    // T*B (scores first)

  // workspace layout (ws ~1 GB per harness poison evidence)
  const size_t WKBF_B  = (size_t)NH * NK * sizeof(short);    // 2 MiB
  const size_t META_B  = 256;
  const size_t RMAP_B  = (size_t)(NTB + 128) * sizeof(unsigned short);
  const size_t QUERY_B = (size_t)NB * NH * sizeof(float);    // 128 KiB
  const size_t EBF_B   = (size_t)NTB * NK * sizeof(short);   // 128 MiB worst case
  short*          Wkbf  = (short*)d_ws;
  int*            meta  = (int*)((char*)d_ws + WKBF_B);
  unsigned short* rmap  = (unsigned short*)((char*)d_ws + WKBF_B + META_B);
  float*          query = (float*)((char*)d_ws + WKBF_B + META_B + RMAP_B);
  short*          Ebf   = (short*)((char*)d_ws + WKBF_B + META_B + RMAP_B + QUERY_B);
  short*          EbfB  = (short*)((char*)d_ws + WKBF_B + META_B + RMAP_B + QUERY_B); // tier-B reuse
  const bool tierA = ws_size >= WKBF_B + META_B + RMAP_B + QUERY_B + EBF_B;
  const bool tierB = ws_size >= WKBF_B + META_B + RMAP_B + QUERY_B + EBF_B; // same bound
  const bool haveQ = ws_size >= WKBF_B + META_B + RMAP_B + QUERY_B;

  hipMemsetAsync(d_out, 0, (size_t)out_size * sizeof(float), stream);

  if (tierA) {
    scan_kernel<<<dim3(1), 1024, 0, stream>>>(mask, rmap, meta);
    prep_kernel<<<dim3(1024), 256, 0, stream>>>(dec, Wq, query, Wk, Wkbf);
    convert_gather_kernel<<<dim3(1024), 256, 0, stream>>>(enc, rmap, meta, Ebf);
    scores_mfma_kernel<<<dim3((NTB / 128) * (NH / 128)), 256, 0, stream>>>(
        Ebf, Wkbf, query, v, alphas, rmap, meta, 1);
    softmax_kernel<<<dim3(NB), 256, 0, stream>>>(mask, alphas);
    context_cbf16_kernel<<<dim3(NK / 512, NB, 32), 256, 0, stream>>>(
        Ebf, rmap, meta, alphas, ctx);
  } else if (tierB) {
    prep_kernel<<<dim3(1024), 256, 0, stream>>>(dec, Wq, query, Wk, Wkbf);
    convert_swz_kernel<<<dim3(2048), 256, 0, stream>>>(enc, EbfB, (long)NTB * NK / 8);
    scores_mfma_kernel<<<dim3((NTB / 128) * (NH / 128)), 256, 0, stream>>>(
        EbfB, Wkbf, query, v, alphas, nullptr, nullptr, 0);
    softmax_kernel<<<dim3(NB), 256, 0, stream>>>(mask, alphas);
    context_f32m_kernel<<<dim3(NK / 256, NB, NT / 128), 256, 0, stream>>>(
        enc, alphas, ctx);
  } else {
    // tier C: minimal-ws fp32 path (query into ws if it fits, else ctx+rezero)
    float* q = haveQ ? query : ctx;
    // reuse prep's query half only via dedicated launch pattern: 512 blocks
    prep_kernel<<<dim3(512), 256, 0, stream>>>(dec, Wq, q, Wk, Wkbf);
    scores_kernel_f32<<<dim3((NTB / 128) * (NH / 128)), 256, 0, stream>>>(
        enc, Wk, q, v, alphas);
    softmax_kernel<<<dim3(NB), 256, 0, stream>>>(mask, alphas);
    if (!haveQ) hipMemsetAsync(ctx, 0, (size_t)NB * NK * sizeof(float), stream);
    context_f32m_kernel<<<dim3(NK / 256, NB, NT / 128), 256, 0, stream>>>(
        enc, alphas, ctx);
  }
}